// Round 8
// baseline (1178.607 us; speedup 1.0000x reference)
//
#include <hip/hip_runtime.h>
#include <hip/hip_bf16.h>

// Problem constants
// inputs [512][4][124][124], conv1 w[32][4][8][8] s4 -> [512][32][30][30]
// conv2 w[64][32][4][4] s2 -> [512][64][14][14]
// conv3 w[32][64][3][3] s1 -> [512][32][12][12] -> flat 4608
// fc [512,4608] -> xs [512][512] relu
// gi = xs @ w_ih^T + b_ih : [512][1536]
// GRU T=32, N=16, H=512 ; heads A=6
// d_out: value[512] | alp[512] | ent[512] | states_out[16*512]

// ---------------- conv1 ----------------
__global__ __launch_bounds__(256) void conv1_k(const float* __restrict__ x,
        const float* __restrict__ w, const float* __restrict__ bias,
        float* __restrict__ out) {
  __shared__ float ws1[8192];               // [32 oc][4 c][8 ky][8 kx]
  for (int i = threadIdx.x; i < 2048; i += 256)
    ((float4*)ws1)[i] = ((const float4*)w)[i];
  __syncthreads();
  int pidx = blockIdx.x * 256 + threadIdx.x;   // [0, 512*450)
  int n = pidx / 450;
  int q = pidx % 450;
  int oy0 = q / 30, ox0 = q % 30;
  int q1 = q + 450;
  int oy1 = q1 / 30, ox1 = q1 % 30;
  float acc0[32], acc1[32];
  #pragma unroll
  for (int oc = 0; oc < 32; ++oc) { float bb = bias[oc] * 255.0f; acc0[oc] = bb; acc1[oc] = bb; }
  for (int c = 0; c < 4; ++c) {
    for (int ky = 0; ky < 8; ++ky) {
      const float* r0 = x + ((n*4 + c)*124 + oy0*4 + ky)*124 + ox0*4;
      const float* r1 = x + ((n*4 + c)*124 + oy1*4 + ky)*124 + ox1*4;
      float4 p0 = *(const float4*)r0, p1 = *(const float4*)(r0 + 4);
      float4 p2 = *(const float4*)r1, p3 = *(const float4*)(r1 + 4);
      float v0[8] = {p0.x,p0.y,p0.z,p0.w,p1.x,p1.y,p1.z,p1.w};
      float v1[8] = {p2.x,p2.y,p2.z,p2.w,p3.x,p3.y,p3.z,p3.w};
      const float* wb = &ws1[c*64 + ky*8];
      #pragma unroll
      for (int oc = 0; oc < 32; ++oc) {
        const float4* wr = (const float4*)(wb + oc*256);   // 16B-aligned
        float4 wa = wr[0], wc = wr[1];
        acc0[oc] += v0[0]*wa.x + v0[1]*wa.y + v0[2]*wa.z + v0[3]*wa.w
                  + v0[4]*wc.x + v0[5]*wc.y + v0[6]*wc.z + v0[7]*wc.w;
        acc1[oc] += v1[0]*wa.x + v1[1]*wa.y + v1[2]*wa.z + v1[3]*wa.w
                  + v1[4]*wc.x + v1[5]*wc.y + v1[6]*wc.z + v1[7]*wc.w;
      }
    }
  }
  const float sc = 1.0f / 255.0f;
  #pragma unroll
  for (int oc = 0; oc < 32; ++oc) {
    out[(n*32 + oc)*900 + q]       = fmaxf(acc0[oc]*sc, 0.f);
    out[(n*32 + oc)*900 + q + 450] = fmaxf(acc1[oc]*sc, 0.f);
  }
}

// ---------------- conv2 ----------------
__global__ __launch_bounds__(256) void conv2_k(const float* __restrict__ in,
        const float* __restrict__ w, const float* __restrict__ bias,
        float* __restrict__ out) {
  __shared__ float ws2[8192];               // 16 oc * 512 ([oc][c][ky][kx4])
  int och0 = blockIdx.y * 16;
  {
    const float4* src = (const float4*)(w + (size_t)och0*512);
    for (int i = threadIdx.x; i < 2048; i += 256) ((float4*)ws2)[i] = src[i];
  }
  __syncthreads();
  int pidx = blockIdx.x * 256 + threadIdx.x;   // [0, 512*98)
  int n = pidx / 98;
  int q = pidx % 98;
  int oy0 = q / 14, ox0 = q % 14;
  int q1 = q + 98;
  int oy1 = q1 / 14, ox1 = q1 % 14;
  float acc0[16], acc1[16];
  #pragma unroll
  for (int oc = 0; oc < 16; ++oc) { float bb = bias[och0 + oc]; acc0[oc] = bb; acc1[oc] = bb; }
  #pragma unroll 2
  for (int c = 0; c < 32; ++c) {
    #pragma unroll
    for (int ky = 0; ky < 4; ++ky) {
      const float* r0 = in + ((n*32 + c)*30 + oy0*2 + ky)*30 + ox0*2;
      const float* r1 = in + ((n*32 + c)*30 + oy1*2 + ky)*30 + ox1*2;
      float v0[4] = {r0[0], r0[1], r0[2], r0[3]};
      float v1[4] = {r1[0], r1[1], r1[2], r1[3]};
      const float* wb = &ws2[c*16 + ky*4];
      #pragma unroll
      for (int oc = 0; oc < 16; ++oc) {
        float4 wv = *(const float4*)(wb + oc*512);   // 16B-aligned
        acc0[oc] += v0[0]*wv.x + v0[1]*wv.y + v0[2]*wv.z + v0[3]*wv.w;
        acc1[oc] += v1[0]*wv.x + v1[1]*wv.y + v1[2]*wv.z + v1[3]*wv.w;
      }
    }
  }
  #pragma unroll
  for (int oc = 0; oc < 16; ++oc) {
    out[(n*64 + och0 + oc)*196 + q]      = fmaxf(acc0[oc], 0.f);
    out[(n*64 + och0 + oc)*196 + q + 98] = fmaxf(acc1[oc], 0.f);
  }
}

// ---------------- conv3 ----------------
__global__ __launch_bounds__(256) void conv3_k(const float* __restrict__ in,
        const float* __restrict__ w, const float* __restrict__ bias,
        float* __restrict__ out) {
  __shared__ float wsT[9216];               // [(c*3+ky)*3+kx][oc]
  int och0 = blockIdx.y * 16;
  for (int i = threadIdx.x; i < 9216; i += 256) {
    int oc = i & 15, rest = i >> 4;
    int kx = rest % 3, t2 = rest / 3;
    int ky = t2 % 3, c = t2 / 3;
    wsT[i] = w[(size_t)(och0 + oc)*576 + c*9 + ky*3 + kx];
  }
  __syncthreads();
  int pidx = blockIdx.x * 256 + threadIdx.x;   // [0, 512*72)
  int n = pidx / 72;
  int q = pidx % 72;
  int oy0 = q / 12, ox0 = q % 12;
  int q1 = q + 72;
  int oy1 = q1 / 12, ox1 = q1 % 12;
  float acc0[16], acc1[16];
  #pragma unroll
  for (int oc = 0; oc < 16; ++oc) { float bb = bias[och0 + oc]; acc0[oc] = bb; acc1[oc] = bb; }
  #pragma unroll 2
  for (int c = 0; c < 64; ++c) {
    #pragma unroll
    for (int ky = 0; ky < 3; ++ky) {
      const float* r0 = in + ((n*64 + c)*14 + oy0 + ky)*14 + ox0;
      const float* r1 = in + ((n*64 + c)*14 + oy1 + ky)*14 + ox1;
      float v0[3] = {r0[0], r0[1], r0[2]};
      float v1[3] = {r1[0], r1[1], r1[2]};
      #pragma unroll
      for (int kx = 0; kx < 3; ++kx) {
        const float4* wp = (const float4*)&wsT[((c*3 + ky)*3 + kx)*16];
        float4 wA = wp[0], wB = wp[1], wC = wp[2], wD = wp[3];
        float a = v0[kx], b = v1[kx];
        acc0[0] += a*wA.x; acc0[1] += a*wA.y; acc0[2]  += a*wA.z; acc0[3]  += a*wA.w;
        acc0[4] += a*wB.x; acc0[5] += a*wB.y; acc0[6]  += a*wB.z; acc0[7]  += a*wB.w;
        acc0[8] += a*wC.x; acc0[9] += a*wC.y; acc0[10] += a*wC.z; acc0[11] += a*wC.w;
        acc0[12]+= a*wD.x; acc0[13]+= a*wD.y; acc0[14] += a*wD.z; acc0[15] += a*wD.w;
        acc1[0] += b*wA.x; acc1[1] += b*wA.y; acc1[2]  += b*wA.z; acc1[3]  += b*wA.w;
        acc1[4] += b*wB.x; acc1[5] += b*wB.y; acc1[6]  += b*wB.z; acc1[7]  += b*wB.w;
        acc1[8] += b*wC.x; acc1[9] += b*wC.y; acc1[10] += b*wC.z; acc1[11] += b*wC.w;
        acc1[12]+= b*wD.x; acc1[13]+= b*wD.y; acc1[14] += b*wD.z; acc1[15] += b*wD.w;
      }
    }
  }
  #pragma unroll
  for (int oc = 0; oc < 16; ++oc) {
    out[(n*32 + och0 + oc)*144 + q]      = fmaxf(acc0[oc], 0.f);
    out[(n*32 + och0 + oc)*144 + q + 72] = fmaxf(acc1[oc], 0.f);
  }
}

// ---------------- GEMM: C[M][N] = A[M][K] * B[N][K]^T + bias, optional ReLU ----------------
template<bool RELU>
__global__ __launch_bounds__(256) void gemm_k(const float* __restrict__ A, const float* __restrict__ B,
                                              const float* __restrict__ bias, float* __restrict__ C,
                                              int M, int N, int K) {
  __shared__ float As[32][33];
  __shared__ float Bs[32][33];
  const int tid = threadIdx.x;
  const int tx = tid & 15, ty = tid >> 4;
  const int m0 = blockIdx.y * 32, n0 = blockIdx.x * 32;
  const int lr = tid >> 3;        // 0..31
  const int lc = (tid & 7) * 4;   // 0..28
  float acc00 = 0.f, acc01 = 0.f, acc10 = 0.f, acc11 = 0.f;
  for (int k0 = 0; k0 < K; k0 += 32) {
    float4 a4 = *(const float4*)(A + (size_t)(m0 + lr)*K + k0 + lc);
    float4 b4 = *(const float4*)(B + (size_t)(n0 + lr)*K + k0 + lc);
    __syncthreads();
    As[lc+0][lr] = a4.x; As[lc+1][lr] = a4.y; As[lc+2][lr] = a4.z; As[lc+3][lr] = a4.w;
    Bs[lc+0][lr] = b4.x; Bs[lc+1][lr] = b4.y; Bs[lc+2][lr] = b4.z; Bs[lc+3][lr] = b4.w;
    __syncthreads();
    #pragma unroll
    for (int kk = 0; kk < 32; ++kk) {
      float a0 = As[kk][ty*2], a1 = As[kk][ty*2+1];
      float b0 = Bs[kk][tx*2], b1 = Bs[kk][tx*2+1];
      acc00 += a0*b0; acc01 += a0*b1; acc10 += a1*b0; acc11 += a1*b1;
    }
  }
  int m = m0 + ty*2, n = n0 + tx*2;
  float bi0 = bias[n], bi1 = bias[n+1];
  float c00 = acc00 + bi0, c01 = acc01 + bi1, c10 = acc10 + bi0, c11 = acc11 + bi1;
  if (RELU) {
    c00 = fmaxf(c00, 0.f); c01 = fmaxf(c01, 0.f);
    c10 = fmaxf(c10, 0.f); c11 = fmaxf(c11, 0.f);
  }
  C[(size_t)m*N + n] = c00;       C[(size_t)m*N + n + 1] = c01;
  C[(size_t)(m+1)*N + n] = c10;   C[(size_t)(m+1)*N + n + 1] = c11;
}

// ---------------- GRU persistent kernel (v7: MFMA + all-store barrier) ----------------
// 32 blocks x 256 threads, MFMA gh (verified r7). Barrier v7: no RMWs.
// Arrive: each block's tid0 STORES flag[b]=t+1 (32 distinct lines, parallel).
// Block 0 wave 0 polls all 32 flags (1 lane each), lane 0 stores go=t+1.
// All other blocks poll only go. All relaxed agent-scope (bypass).
// flags layout (ints): [0]=go, [32 + b*16]=per-block flag.
typedef __bf16 bf16x8_t __attribute__((ext_vector_type(8)));
typedef float  f32x4_t  __attribute__((ext_vector_type(4)));

__device__ __forceinline__ unsigned int pack_bf2(float a, float b) {
  union { __bf16 h[2]; unsigned int u; } c;
  c.h[0] = (__bf16)a; c.h[1] = (__bf16)b;
  return c.u;
}

#define GRU_NB 32
__global__ __launch_bounds__(256) void gru_k(const float* __restrict__ gi, const float* __restrict__ states,
    const float* __restrict__ masks, const float* __restrict__ w_hh, const float* __restrict__ b_hh,
    float* __restrict__ outs, float* __restrict__ hbuf, int* __restrict__ flags,
    float* __restrict__ states_out) {
  __shared__ __align__(16) unsigned short hbf[16*516];  // h bf16, stride 516
  __shared__ float hp_s[16*16];     // [n][j] fp32 masked h for own j-slice
  __shared__ float gh_s[48*17];     // [g*16+j][n], stride 17
  __shared__ float bhs[48];
  __shared__ float mask_s[512];
  const int b    = blockIdx.x;
  const int tid  = threadIdx.x;
  const int lane = tid & 63;
  const int wv   = tid >> 6;
  const int jbase = b * 16;
  const int n2 = tid & 15;          // gate-phase mapping
  const int j2 = tid >> 4;
  int* go = flags;

  for (int i = tid; i < 512; i += 256) mask_s[i] = masks[i];
  if (tid < 48) bhs[tid] = b_hh[(tid >> 4)*512 + jbase + (tid & 15)];

  // ---- preload w_hh A-frags into registers (waves 0..2; wave g = gate g) ----
  bf16x8_t wfr[16];
  {
    int r = lane & 15, q = lane >> 4;
    int g = (wv < 3) ? wv : 0;
    const float* wrow = w_hh + (size_t)(g*512 + jbase + r)*512 + q*8;
    #pragma unroll
    for (int ks = 0; ks < 16; ++ks) {
      float4 f0 = *(const float4*)(wrow + ks*32);
      float4 f1 = *(const float4*)(wrow + ks*32 + 4);
      bf16x8_t v;
      v[0] = (__bf16)f0.x; v[1] = (__bf16)f0.y; v[2] = (__bf16)f0.z; v[3] = (__bf16)f0.w;
      v[4] = (__bf16)f1.x; v[5] = (__bf16)f1.y; v[6] = (__bf16)f1.z; v[7] = (__bf16)f1.w;
      wfr[ks] = v;
    }
  }
  __syncthreads();   // mask_s ready

  for (int t = 0; t < 32; ++t) {
    // ---- gi prefetch for this step ----
    const float* gir_p = gi + (size_t)(t*16 + n2)*1536 + jbase + j2;
    float g_r = gir_p[0];
    float g_z = gir_p[512];
    float g_n = gir_p[1024];
    // ---- stage masked h as bf16 into LDS ----
    if (t == 0) {
      for (int i = tid; i < 4096; i += 256) {
        int nn = i >> 8, kp = (i & 255) * 2;
        float m = mask_s[nn];
        float f0 = states[nn*512 + kp], f1 = states[nn*512 + kp + 1];
        *(unsigned int*)&hbf[nn*516 + kp] = pack_bf2(f0*m, f1*m);
      }
      hp_s[n2*16 + j2] = states[n2*512 + jbase + j2] * mask_s[n2];
    } else {
      const unsigned long long* hsrc = (const unsigned long long*)(hbuf + (t & 1)*8192);
      for (int i = tid; i < 4096; i += 256) {
        int nn = i >> 8, kp = (i & 255) * 2;
        unsigned long long u = __hip_atomic_load(hsrc + i, __ATOMIC_RELAXED, __HIP_MEMORY_SCOPE_AGENT);
        union { unsigned long long u; float f[2]; } cv; cv.u = u;
        float m = mask_s[t*16 + nn];
        *(unsigned int*)&hbf[nn*516 + kp] = pack_bf2(cv.f[0]*m, cv.f[1]*m);
      }
    }
    __syncthreads();
    // ---- gh via MFMA: wave g computes gate-g 16x16 tile over K=512 ----
    if (wv < 3) {
      int r = lane & 15, q = lane >> 4;
      f32x4_t acc = {0.f, 0.f, 0.f, 0.f};
      const unsigned short* hrow = &hbf[r*516 + q*8];
      #pragma unroll
      for (int ks = 0; ks < 16; ++ks) {
        union { bf16x8_t v; uint2 u[2]; } fb;
        fb.u[0] = *(const uint2*)(hrow + ks*32);
        fb.u[1] = *(const uint2*)(hrow + ks*32 + 4);
        acc = __builtin_amdgcn_mfma_f32_16x16x32_bf16(wfr[ks], fb.v, acc, 0, 0, 0);
      }
      // D layout: col(n) = lane&15, row(m=j-local) = (lane>>4)*4 + reg
      #pragma unroll
      for (int rg = 0; rg < 4; ++rg)
        gh_s[(wv*16 + q*4 + rg)*17 + r] = acc[rg];
    }
    __syncthreads();
    // ---- gates (all 256 threads: thread = (n2, j2)) ----
    {
      float ghr = gh_s[(j2)*17 + n2]      + bhs[j2];
      float ghz = gh_s[(16 + j2)*17 + n2] + bhs[16 + j2];
      float ghn = gh_s[(32 + j2)*17 + n2] + bhs[32 + j2];
      float rg = 1.f / (1.f + expf(-(g_r + ghr)));
      float zg = 1.f / (1.f + expf(-(g_z + ghz)));
      float ng = tanhf(g_n + rg*ghn);
      float hp = hp_s[n2*16 + j2];
      float hn = (1.f - zg)*ng + zg*hp;
      outs[(size_t)(t*16 + n2)*512 + jbase + j2] = hn;
      if (t < 31) {
        __hip_atomic_store(hbuf + ((t+1)&1)*8192 + n2*512 + jbase + j2, hn,
                           __ATOMIC_RELAXED, __HIP_MEMORY_SCOPE_AGENT);
        hp_s[n2*16 + j2] = hn * mask_s[(t+1)*16 + n2];
      } else {
        states_out[n2*512 + jbase + j2] = hn;
      }
    }
    // ---- all-store grid barrier (no RMWs) ----
    if (t < 31) {
      __syncthreads();                 // drains all 256 threads' h stores (vmcnt 0)
      const int target = t + 1;
      if (tid == 0)
        __hip_atomic_store(&flags[32 + b*16], target, __ATOMIC_RELAXED, __HIP_MEMORY_SCOPE_AGENT);
      if (b == 0) {
        if (tid < 64) {                // wave 0 of block 0 gathers 32 flags
          int done = 0;
          while (!done) {
            int ok = 1;
            if (tid < 32) {
              int v = __hip_atomic_load(&flags[32 + tid*16], __ATOMIC_RELAXED, __HIP_MEMORY_SCOPE_AGENT);
              ok = (v >= target);
            }
            done = __all(ok);
            if (!done) __builtin_amdgcn_s_sleep(1);
          }
          if (tid == 0)
            __hip_atomic_store(go, target, __ATOMIC_RELAXED, __HIP_MEMORY_SCOPE_AGENT);
        }
      } else if (tid == 0) {
        while (__hip_atomic_load(go, __ATOMIC_RELAXED, __HIP_MEMORY_SCOPE_AGENT) < target)
          __builtin_amdgcn_s_sleep(1);
      }
      __syncthreads();
    }
  }
}

// ---------------- heads ----------------
__global__ __launch_bounds__(256) void heads_k(const float* __restrict__ xs, const int* __restrict__ action,
    const float* __restrict__ aw, const float* __restrict__ ab,
    const float* __restrict__ cw, const float* __restrict__ cb, float* __restrict__ out) {
  int row  = blockIdx.x * 4 + (threadIdx.x >> 6);
  int lane = threadIdx.x & 63;
  const float* xr = xs + (size_t)row * 512;
  float acc[7];
  #pragma unroll
  for (int a = 0; a < 7; ++a) acc[a] = 0.f;
  #pragma unroll
  for (int kb = 0; kb < 8; ++kb) {
    int k = kb*64 + lane;
    float xv = xr[k];
    #pragma unroll
    for (int a = 0; a < 6; ++a) acc[a] += xv * aw[a*512 + k];
    acc[6] += xv * cw[k];
  }
  #pragma unroll
  for (int off = 32; off > 0; off >>= 1) {
    #pragma unroll
    for (int a = 0; a < 7; ++a) acc[a] += __shfl_down(acc[a], off);
  }
  if (lane == 0) {
    float lg[6];
    #pragma unroll
    for (int a = 0; a < 6; ++a) lg[a] = acc[a] + ab[a];
    float mx = lg[0];
    #pragma unroll
    for (int a = 1; a < 6; ++a) mx = fmaxf(mx, lg[a]);
    float se = 0.f;
    #pragma unroll
    for (int a = 0; a < 6; ++a) se += expf(lg[a] - mx);
    float lse = mx + logf(se);
    float ent = 0.f;
    #pragma unroll
    for (int a = 0; a < 6; ++a) { float lp = lg[a] - lse; ent -= expf(lp)*lp; }
    int ai = action[row];
    out[row]        = acc[6] + cb[0];
    out[512  + row] = lg[ai] - lse;
    out[1024 + row] = ent;
  }
}

extern "C" void kernel_launch(void* const* d_in, const int* in_sizes, int n_in,
                              void* d_out, int out_size, void* d_ws, size_t ws_size,
                              hipStream_t stream) {
  const float* x      = (const float*)d_in[0];
  const float* states = (const float*)d_in[1];
  const float* masks  = (const float*)d_in[2];
  const int*   action = (const int*)d_in[3];
  const float* c1w = (const float*)d_in[4];
  const float* c1b = (const float*)d_in[5];
  const float* c2w = (const float*)d_in[6];
  const float* c2b = (const float*)d_in[7];
  const float* c3w = (const float*)d_in[8];
  const float* c3b = (const float*)d_in[9];
  const float* fcw = (const float*)d_in[10];
  const float* fcb = (const float*)d_in[11];
  const float* wih = (const float*)d_in[12];
  const float* whh = (const float*)d_in[13];
  const float* bih = (const float*)d_in[14];
  const float* bhh = (const float*)d_in[15];
  const float* aw  = (const float*)d_in[16];
  const float* ab  = (const float*)d_in[17];
  const float* cw  = (const float*)d_in[18];
  const float* cb  = (const float*)d_in[19];
  (void)in_sizes; (void)n_in; (void)out_size; (void)ws_size;

  float* ws = (float*)d_ws;
  float* o1    = ws;
  float* o2    = ws + 14745600;
  float* o3    = ws;
  float* xs    = ws + 2359296;
  float* gibuf = ws + 2621440;
  float* outs  = ws + 3407872;
  float* hbuf  = ws + 3670016;
  int*   flags = (int*)(ws + 3686400);
  float* out   = (float*)d_out;

  conv1_k<<<900, 256, 0, stream>>>(x, c1w, c1b, o1);
  conv2_k<<<dim3(196, 4), 256, 0, stream>>>(o1, c2w, c2b, o2);
  conv3_k<<<dim3(144, 2), 256, 0, stream>>>(o2, c3w, c3b, o3);
  gemm_k<true ><<<dim3(16, 16), 256, 0, stream>>>(o3, fcw, fcb, xs, 512, 512, 4608);
  gemm_k<false><<<dim3(48, 16), 256, 0, stream>>>(xs, wih, bih, gibuf, 512, 1536, 512);
  hipMemsetAsync(flags, 0, 1024 * sizeof(int), stream);
  gru_k<<<GRU_NB, 256, 0, stream>>>(gibuf, states, masks, whh, bhh, outs, hbuf, flags, out + 1536);
  heads_k<<<128, 256, 0, stream>>>(outs, action, aw, ab, cw, cb, out);
}

// Round 9
// 885.537 us; speedup vs baseline: 1.3310x; 1.3310x over previous
//
#include <hip/hip_runtime.h>
#include <hip/hip_bf16.h>

// Problem constants
// inputs [512][4][124][124], conv1 w[32][4][8][8] s4 -> [512][32][30][30] (bf16 out)
// conv2 w[64][32][4][4] s2 -> [512][64][14][14]   (MFMA implicit GEMM)
// conv3 w[32][64][3][3] s1 -> [512][32][12][12] -> flat 4608
// fc [512,4608] -> xs [512][512] relu
// gi = xs @ w_ih^T + b_ih : [512][1536]
// GRU T=32, N=16, H=512 ; heads A=6
// d_out: value[512] | alp[512] | ent[512] | states_out[16*512]

typedef __bf16 bf16x8_t __attribute__((ext_vector_type(8)));
typedef float  f32x4_t  __attribute__((ext_vector_type(4)));

__device__ __forceinline__ unsigned int pack_bf2(float a, float b) {
  union { __bf16 h[2]; unsigned int u; } c;
  c.h[0] = (__bf16)a; c.h[1] = (__bf16)b;
  return c.u;
}
__device__ __forceinline__ unsigned short f2bf(float x) {
  union { __bf16 h; unsigned short s; } c; c.h = (__bf16)x; return c.s;
}

// ---------------- conv1 (fp32 compute, bf16 output) ----------------
__global__ __launch_bounds__(256) void conv1_k(const float* __restrict__ x,
        const float* __restrict__ w, const float* __restrict__ bias,
        unsigned short* __restrict__ out) {
  __shared__ float ws1[8192];               // [32 oc][4 c][8 ky][8 kx]
  for (int i = threadIdx.x; i < 2048; i += 256)
    ((float4*)ws1)[i] = ((const float4*)w)[i];
  __syncthreads();
  int pidx = blockIdx.x * 256 + threadIdx.x;   // [0, 512*450)
  int n = pidx / 450;
  int q = pidx % 450;
  int oy0 = q / 30, ox0 = q % 30;
  int q1 = q + 450;
  int oy1 = q1 / 30, ox1 = q1 % 30;
  float acc0[32], acc1[32];
  #pragma unroll
  for (int oc = 0; oc < 32; ++oc) { float bb = bias[oc] * 255.0f; acc0[oc] = bb; acc1[oc] = bb; }
  for (int c = 0; c < 4; ++c) {
    for (int ky = 0; ky < 8; ++ky) {
      const float* r0 = x + ((n*4 + c)*124 + oy0*4 + ky)*124 + ox0*4;
      const float* r1 = x + ((n*4 + c)*124 + oy1*4 + ky)*124 + ox1*4;
      float4 p0 = *(const float4*)r0, p1 = *(const float4*)(r0 + 4);
      float4 p2 = *(const float4*)r1, p3 = *(const float4*)(r1 + 4);
      float v0[8] = {p0.x,p0.y,p0.z,p0.w,p1.x,p1.y,p1.z,p1.w};
      float v1[8] = {p2.x,p2.y,p2.z,p2.w,p3.x,p3.y,p3.z,p3.w};
      const float* wb = &ws1[c*64 + ky*8];
      #pragma unroll
      for (int oc = 0; oc < 32; ++oc) {
        const float4* wr = (const float4*)(wb + oc*256);   // 16B-aligned
        float4 wa = wr[0], wc = wr[1];
        acc0[oc] += v0[0]*wa.x + v0[1]*wa.y + v0[2]*wa.z + v0[3]*wa.w
                  + v0[4]*wc.x + v0[5]*wc.y + v0[6]*wc.z + v0[7]*wc.w;
        acc1[oc] += v1[0]*wa.x + v1[1]*wa.y + v1[2]*wa.z + v1[3]*wa.w
                  + v1[4]*wc.x + v1[5]*wc.y + v1[6]*wc.z + v1[7]*wc.w;
      }
    }
  }
  const float sc = 1.0f / 255.0f;
  #pragma unroll
  for (int oc = 0; oc < 32; ++oc) {
    out[(n*32 + oc)*900 + q]       = f2bf(fmaxf(acc0[oc]*sc, 0.f));
    out[(n*32 + oc)*900 + q + 450] = f2bf(fmaxf(acc1[oc]*sc, 0.f));
  }
}

// ---------------- conv2: bf16 MFMA implicit GEMM ----------------
// M = 512*196 = 100352 px, N = 64 oc, K = 32c*4ky*4kx = 512.
// 1568 blocks x 256 thr. Block: 64 px. Wave w: oc-tile [16w,16w+16).
// Patches im2col'd to LDS bf16 [64 px][520]; weights as 16 A-frags in regs.
__global__ __launch_bounds__(256) void conv2_mfma(const unsigned short* __restrict__ in,
        const float* __restrict__ w, const float* __restrict__ bias,
        float* __restrict__ out) {
  __shared__ __align__(16) unsigned short pt[64*520];   // 65 KB
  const int tid  = threadIdx.x;
  const int lane = tid & 63;
  const int wv   = tid >> 6;
  const int px0  = blockIdx.x * 64;
  // ---- staging: lane = px-local; wave wv covers c in [8wv, 8wv+8) ----
  {
    int px = px0 + lane;
    int n = px / 196, q = px % 196;
    int oy = q / 14, ox = q % 14;
    const unsigned short* base = in + ((size_t)(n*32)*30 + oy*2)*30 + ox*2;
    #pragma unroll 4
    for (int it = 0; it < 32; ++it) {
      int c  = wv*8 + (it >> 2);
      int ky = it & 3;
      const unsigned short* src = base + (c*30 + ky)*30;
      unsigned int a0 = *(const unsigned int*)(src);      // 4B-aligned (even idx)
      unsigned int a1 = *(const unsigned int*)(src + 2);
      *(uint2*)&pt[lane*520 + c*16 + ky*4] = make_uint2(a0, a1);
    }
  }
  // ---- weights -> 16 A-frags (fp32 global, L2-resident; cvt to bf16) ----
  bf16x8_t wfr[16];
  {
    int m = lane & 15, q = lane >> 4;
    const float* wrow = w + (size_t)(wv*16 + m)*512 + q*8;
    #pragma unroll
    for (int ks = 0; ks < 16; ++ks) {
      float4 f0 = *(const float4*)(wrow + ks*32);
      float4 f1 = *(const float4*)(wrow + ks*32 + 4);
      bf16x8_t v;
      v[0] = (__bf16)f0.x; v[1] = (__bf16)f0.y; v[2] = (__bf16)f0.z; v[3] = (__bf16)f0.w;
      v[4] = (__bf16)f1.x; v[5] = (__bf16)f1.y; v[6] = (__bf16)f1.z; v[7] = (__bf16)f1.w;
      wfr[ks] = v;
    }
  }
  __syncthreads();
  // ---- MFMA: 4 px-tiles x 16 ksteps ----
  f32x4_t acc[4];
  #pragma unroll
  for (int pxt = 0; pxt < 4; ++pxt) {
    f32x4_t a = {0.f, 0.f, 0.f, 0.f};
    const unsigned short* prow = &pt[(pxt*16 + (lane & 15))*520 + (lane >> 4)*8];
    #pragma unroll
    for (int ks = 0; ks < 16; ++ks) {
      union { bf16x8_t v; uint4 u; } fb;
      fb.u = *(const uint4*)(prow + ks*32);   // 16B-aligned (stride 1040B)
      a = __builtin_amdgcn_mfma_f32_16x16x32_bf16(wfr[ks], fb.v, a, 0, 0, 0);
    }
    acc[pxt] = a;
  }
  // ---- epilogue: D col = px-local (lane&15), row = oc-local (lane>>4)*4+rg ----
  {
    int q4 = lane >> 4;
    float b4[4];
    #pragma unroll
    for (int rg = 0; rg < 4; ++rg) b4[rg] = bias[wv*16 + q4*4 + rg];
    #pragma unroll
    for (int pxt = 0; pxt < 4; ++pxt) {
      int px = px0 + pxt*16 + (lane & 15);
      int n = px / 196, q = px % 196;
      #pragma unroll
      for (int rg = 0; rg < 4; ++rg) {
        int oc = wv*16 + q4*4 + rg;
        out[((size_t)n*64 + oc)*196 + q] = fmaxf(acc[pxt][rg] + b4[rg], 0.f);
      }
    }
  }
}

// ---------------- conv3 (r7 version, fp32) ----------------
__global__ __launch_bounds__(256) void conv3_k(const float* __restrict__ in,
        const float* __restrict__ w, const float* __restrict__ bias,
        float* __restrict__ out) {
  __shared__ float wsT[9216];               // [(c*3+ky)*3+kx][oc]
  int och0 = blockIdx.y * 16;
  for (int i = threadIdx.x; i < 9216; i += 256) {
    int oc = i & 15, rest = i >> 4;
    int kx = rest % 3, t2 = rest / 3;
    int ky = t2 % 3, c = t2 / 3;
    wsT[i] = w[(size_t)(och0 + oc)*576 + c*9 + ky*3 + kx];
  }
  __syncthreads();
  int pidx = blockIdx.x * 256 + threadIdx.x;   // [0, 512*72)
  int n = pidx / 72;
  int q = pidx % 72;
  int oy0 = q / 12, ox0 = q % 12;
  int q1 = q + 72;
  int oy1 = q1 / 12, ox1 = q1 % 12;
  float acc0[16], acc1[16];
  #pragma unroll
  for (int oc = 0; oc < 16; ++oc) { float bb = bias[och0 + oc]; acc0[oc] = bb; acc1[oc] = bb; }
  for (int c = 0; c < 64; ++c) {
    #pragma unroll
    for (int ky = 0; ky < 3; ++ky) {
      const float* r0 = in + ((n*64 + c)*14 + oy0 + ky)*14 + ox0;
      const float* r1 = in + ((n*64 + c)*14 + oy1 + ky)*14 + ox1;
      float v0[3] = {r0[0], r0[1], r0[2]};
      float v1[3] = {r1[0], r1[1], r1[2]};
      #pragma unroll
      for (int kx = 0; kx < 3; ++kx) {
        const float4* wp = (const float4*)&wsT[((c*3 + ky)*3 + kx)*16];
        float4 wA = wp[0], wB = wp[1], wC = wp[2], wD = wp[3];
        float a = v0[kx], b = v1[kx];
        acc0[0] += a*wA.x; acc0[1] += a*wA.y; acc0[2]  += a*wA.z; acc0[3]  += a*wA.w;
        acc0[4] += a*wB.x; acc0[5] += a*wB.y; acc0[6]  += a*wB.z; acc0[7]  += a*wB.w;
        acc0[8] += a*wC.x; acc0[9] += a*wC.y; acc0[10] += a*wC.z; acc0[11] += a*wC.w;
        acc0[12]+= a*wD.x; acc0[13]+= a*wD.y; acc0[14] += a*wD.z; acc0[15] += a*wD.w;
        acc1[0] += b*wA.x; acc1[1] += b*wA.y; acc1[2]  += b*wA.z; acc1[3]  += b*wA.w;
        acc1[4] += b*wB.x; acc1[5] += b*wB.y; acc1[6]  += b*wB.z; acc1[7]  += b*wB.w;
        acc1[8] += b*wC.x; acc1[9] += b*wC.y; acc1[10] += b*wC.z; acc1[11] += b*wC.w;
        acc1[12]+= b*wD.x; acc1[13]+= b*wD.y; acc1[14] += b*wD.z; acc1[15] += b*wD.w;
      }
    }
  }
  #pragma unroll
  for (int oc = 0; oc < 16; ++oc) {
    out[(n*32 + och0 + oc)*144 + q]      = fmaxf(acc0[oc], 0.f);
    out[(n*32 + och0 + oc)*144 + q + 72] = fmaxf(acc1[oc], 0.f);
  }
}

// ---------------- GEMM: C[M][N] = A[M][K] * B[N][K]^T + bias, optional ReLU ----------------
template<bool RELU>
__global__ __launch_bounds__(256) void gemm_k(const float* __restrict__ A, const float* __restrict__ B,
                                              const float* __restrict__ bias, float* __restrict__ C,
                                              int M, int N, int K) {
  __shared__ float As[32][33];
  __shared__ float Bs[32][33];
  const int tid = threadIdx.x;
  const int tx = tid & 15, ty = tid >> 4;
  const int m0 = blockIdx.y * 32, n0 = blockIdx.x * 32;
  const int lr = tid >> 3;        // 0..31
  const int lc = (tid & 7) * 4;   // 0..28
  float acc00 = 0.f, acc01 = 0.f, acc10 = 0.f, acc11 = 0.f;
  for (int k0 = 0; k0 < K; k0 += 32) {
    float4 a4 = *(const float4*)(A + (size_t)(m0 + lr)*K + k0 + lc);
    float4 b4 = *(const float4*)(B + (size_t)(n0 + lr)*K + k0 + lc);
    __syncthreads();
    As[lc+0][lr] = a4.x; As[lc+1][lr] = a4.y; As[lc+2][lr] = a4.z; As[lc+3][lr] = a4.w;
    Bs[lc+0][lr] = b4.x; Bs[lc+1][lr] = b4.y; Bs[lc+2][lr] = b4.z; Bs[lc+3][lr] = b4.w;
    __syncthreads();
    #pragma unroll
    for (int kk = 0; kk < 32; ++kk) {
      float a0 = As[kk][ty*2], a1 = As[kk][ty*2+1];
      float b0 = Bs[kk][tx*2], b1 = Bs[kk][tx*2+1];
      acc00 += a0*b0; acc01 += a0*b1; acc10 += a1*b0; acc11 += a1*b1;
    }
  }
  int m = m0 + ty*2, n = n0 + tx*2;
  float bi0 = bias[n], bi1 = bias[n+1];
  float c00 = acc00 + bi0, c01 = acc01 + bi1, c10 = acc10 + bi0, c11 = acc11 + bi1;
  if (RELU) {
    c00 = fmaxf(c00, 0.f); c01 = fmaxf(c01, 0.f);
    c10 = fmaxf(c10, 0.f); c11 = fmaxf(c11, 0.f);
  }
  C[(size_t)m*N + n] = c00;       C[(size_t)m*N + n + 1] = c01;
  C[(size_t)(m+1)*N + n] = c10;   C[(size_t)(m+1)*N + n + 1] = c11;
}

// ---------------- GRU persistent kernel (v7: MFMA + all-store barrier) ----------------
#define GRU_NB 32
__global__ __launch_bounds__(256) void gru_k(const float* __restrict__ gi, const float* __restrict__ states,
    const float* __restrict__ masks, const float* __restrict__ w_hh, const float* __restrict__ b_hh,
    float* __restrict__ outs, float* __restrict__ hbuf, int* __restrict__ flags,
    float* __restrict__ states_out) {
  __shared__ __align__(16) unsigned short hbf[16*516];  // h bf16, stride 516
  __shared__ float hp_s[16*16];
  __shared__ float gh_s[48*17];
  __shared__ float bhs[48];
  __shared__ float mask_s[512];
  const int b    = blockIdx.x;
  const int tid  = threadIdx.x;
  const int lane = tid & 63;
  const int wv   = tid >> 6;
  const int jbase = b * 16;
  const int n2 = tid & 15;
  const int j2 = tid >> 4;
  int* go = flags;

  for (int i = tid; i < 512; i += 256) mask_s[i] = masks[i];
  if (tid < 48) bhs[tid] = b_hh[(tid >> 4)*512 + jbase + (tid & 15)];

  bf16x8_t wfr[16];
  {
    int r = lane & 15, q = lane >> 4;
    int g = (wv < 3) ? wv : 0;
    const float* wrow = w_hh + (size_t)(g*512 + jbase + r)*512 + q*8;
    #pragma unroll
    for (int ks = 0; ks < 16; ++ks) {
      float4 f0 = *(const float4*)(wrow + ks*32);
      float4 f1 = *(const float4*)(wrow + ks*32 + 4);
      bf16x8_t v;
      v[0] = (__bf16)f0.x; v[1] = (__bf16)f0.y; v[2] = (__bf16)f0.z; v[3] = (__bf16)f0.w;
      v[4] = (__bf16)f1.x; v[5] = (__bf16)f1.y; v[6] = (__bf16)f1.z; v[7] = (__bf16)f1.w;
      wfr[ks] = v;
    }
  }
  __syncthreads();

  for (int t = 0; t < 32; ++t) {
    const float* gir_p = gi + (size_t)(t*16 + n2)*1536 + jbase + j2;
    float g_r = gir_p[0];
    float g_z = gir_p[512];
    float g_n = gir_p[1024];
    if (t == 0) {
      for (int i = tid; i < 4096; i += 256) {
        int nn = i >> 8, kp = (i & 255) * 2;
        float m = mask_s[nn];
        float f0 = states[nn*512 + kp], f1 = states[nn*512 + kp + 1];
        *(unsigned int*)&hbf[nn*516 + kp] = pack_bf2(f0*m, f1*m);
      }
      hp_s[n2*16 + j2] = states[n2*512 + jbase + j2] * mask_s[n2];
    } else {
      const unsigned long long* hsrc = (const unsigned long long*)(hbuf + (t & 1)*8192);
      for (int i = tid; i < 4096; i += 256) {
        int nn = i >> 8, kp = (i & 255) * 2;
        unsigned long long u = __hip_atomic_load(hsrc + i, __ATOMIC_RELAXED, __HIP_MEMORY_SCOPE_AGENT);
        union { unsigned long long u; float f[2]; } cv; cv.u = u;
        float m = mask_s[t*16 + nn];
        *(unsigned int*)&hbf[nn*516 + kp] = pack_bf2(cv.f[0]*m, cv.f[1]*m);
      }
    }
    __syncthreads();
    if (wv < 3) {
      int r = lane & 15, q = lane >> 4;
      f32x4_t acc = {0.f, 0.f, 0.f, 0.f};
      const unsigned short* hrow = &hbf[r*516 + q*8];
      #pragma unroll
      for (int ks = 0; ks < 16; ++ks) {
        union { bf16x8_t v; uint2 u[2]; } fb;
        fb.u[0] = *(const uint2*)(hrow + ks*32);
        fb.u[1] = *(const uint2*)(hrow + ks*32 + 4);
        acc = __builtin_amdgcn_mfma_f32_16x16x32_bf16(wfr[ks], fb.v, acc, 0, 0, 0);
      }
      #pragma unroll
      for (int rg = 0; rg < 4; ++rg)
        gh_s[(wv*16 + q*4 + rg)*17 + r] = acc[rg];
    }
    __syncthreads();
    {
      float ghr = gh_s[(j2)*17 + n2]      + bhs[j2];
      float ghz = gh_s[(16 + j2)*17 + n2] + bhs[16 + j2];
      float ghn = gh_s[(32 + j2)*17 + n2] + bhs[32 + j2];
      float rg = 1.f / (1.f + expf(-(g_r + ghr)));
      float zg = 1.f / (1.f + expf(-(g_z + ghz)));
      float ng = tanhf(g_n + rg*ghn);
      float hp = hp_s[n2*16 + j2];
      float hn = (1.f - zg)*ng + zg*hp;
      outs[(size_t)(t*16 + n2)*512 + jbase + j2] = hn;
      if (t < 31) {
        __hip_atomic_store(hbuf + ((t+1)&1)*8192 + n2*512 + jbase + j2, hn,
                           __ATOMIC_RELAXED, __HIP_MEMORY_SCOPE_AGENT);
        hp_s[n2*16 + j2] = hn * mask_s[(t+1)*16 + n2];
      } else {
        states_out[n2*512 + jbase + j2] = hn;
      }
    }
    if (t < 31) {
      __syncthreads();
      const int target = t + 1;
      if (tid == 0)
        __hip_atomic_store(&flags[32 + b*16], target, __ATOMIC_RELAXED, __HIP_MEMORY_SCOPE_AGENT);
      if (b == 0) {
        if (tid < 64) {
          int done = 0;
          while (!done) {
            int ok = 1;
            if (tid < 32) {
              int v = __hip_atomic_load(&flags[32 + tid*16], __ATOMIC_RELAXED, __HIP_MEMORY_SCOPE_AGENT);
              ok = (v >= target);
            }
            done = __all(ok);
            if (!done) __builtin_amdgcn_s_sleep(1);
          }
          if (tid == 0)
            __hip_atomic_store(go, target, __ATOMIC_RELAXED, __HIP_MEMORY_SCOPE_AGENT);
        }
      } else if (tid == 0) {
        while (__hip_atomic_load(go, __ATOMIC_RELAXED, __HIP_MEMORY_SCOPE_AGENT) < target)
          __builtin_amdgcn_s_sleep(1);
      }
      __syncthreads();
    }
  }
}

// ---------------- heads ----------------
__global__ __launch_bounds__(256) void heads_k(const float* __restrict__ xs, const int* __restrict__ action,
    const float* __restrict__ aw, const float* __restrict__ ab,
    const float* __restrict__ cw, const float* __restrict__ cb, float* __restrict__ out) {
  int row  = blockIdx.x * 4 + (threadIdx.x >> 6);
  int lane = threadIdx.x & 63;
  const float* xr = xs + (size_t)row * 512;
  float acc[7];
  #pragma unroll
  for (int a = 0; a < 7; ++a) acc[a] = 0.f;
  #pragma unroll
  for (int kb = 0; kb < 8; ++kb) {
    int k = kb*64 + lane;
    float xv = xr[k];
    #pragma unroll
    for (int a = 0; a < 6; ++a) acc[a] += xv * aw[a*512 + k];
    acc[6] += xv * cw[k];
  }
  #pragma unroll
  for (int off = 32; off > 0; off >>= 1) {
    #pragma unroll
    for (int a = 0; a < 7; ++a) acc[a] += __shfl_down(acc[a], off);
  }
  if (lane == 0) {
    float lg[6];
    #pragma unroll
    for (int a = 0; a < 6; ++a) lg[a] = acc[a] + ab[a];
    float mx = lg[0];
    #pragma unroll
    for (int a = 1; a < 6; ++a) mx = fmaxf(mx, lg[a]);
    float se = 0.f;
    #pragma unroll
    for (int a = 0; a < 6; ++a) se += expf(lg[a] - mx);
    float lse = mx + logf(se);
    float ent = 0.f;
    #pragma unroll
    for (int a = 0; a < 6; ++a) { float lp = lg[a] - lse; ent -= expf(lp)*lp; }
    int ai = action[row];
    out[row]        = acc[6] + cb[0];
    out[512  + row] = lg[ai] - lse;
    out[1024 + row] = ent;
  }
}

extern "C" void kernel_launch(void* const* d_in, const int* in_sizes, int n_in,
                              void* d_out, int out_size, void* d_ws, size_t ws_size,
                              hipStream_t stream) {
  const float* x      = (const float*)d_in[0];
  const float* states = (const float*)d_in[1];
  const float* masks  = (const float*)d_in[2];
  const int*   action = (const int*)d_in[3];
  const float* c1w = (const float*)d_in[4];
  const float* c1b = (const float*)d_in[5];
  const float* c2w = (const float*)d_in[6];
  const float* c2b = (const float*)d_in[7];
  const float* c3w = (const float*)d_in[8];
  const float* c3b = (const float*)d_in[9];
  const float* fcw = (const float*)d_in[10];
  const float* fcb = (const float*)d_in[11];
  const float* wih = (const float*)d_in[12];
  const float* whh = (const float*)d_in[13];
  const float* bih = (const float*)d_in[14];
  const float* bhh = (const float*)d_in[15];
  const float* aw  = (const float*)d_in[16];
  const float* ab  = (const float*)d_in[17];
  const float* cw  = (const float*)d_in[18];
  const float* cb  = (const float*)d_in[19];
  (void)in_sizes; (void)n_in; (void)out_size; (void)ws_size;

  float* ws = (float*)d_ws;
  unsigned short* o1b = (unsigned short*)ws;     // bf16, 14.7M ushorts (fits in o1 region)
  float* o2    = ws + 14745600;
  float* o3    = ws;                             // reuse: conv2 done before? No -> see order
  float* xs    = ws + 2359296;
  float* gibuf = ws + 2621440;
  float* outs  = ws + 3407872;
  float* hbuf  = ws + 3670016;
  int*   flags = (int*)(ws + 3686400);
  float* out   = (float*)d_out;
  // NOTE: o3 overlaps o1b region, but conv3 runs after conv2 consumed o1b,
  // and o3 (2.36M floats) < o1b region (14.7M ushorts = 7.37M floats): conv3
  // writes while no one reads o1b anymore. Same scheme as earlier rounds.

  conv1_k<<<900, 256, 0, stream>>>(x, c1w, c1b, o1b);
  conv2_mfma<<<1568, 256, 0, stream>>>(o1b, c2w, c2b, o2);
  conv3_k<<<dim3(144, 2), 256, 0, stream>>>(o2, c3w, c3b, o3);
  gemm_k<true ><<<dim3(16, 16), 256, 0, stream>>>(o3, fcw, fcb, xs, 512, 512, 4608);
  gemm_k<false><<<dim3(48, 16), 256, 0, stream>>>(xs, wih, bih, gibuf, 512, 1536, 512);
  hipMemsetAsync(flags, 0, 1024 * sizeof(int), stream);
  gru_k<<<GRU_NB, 256, 0, stream>>>(gibuf, states, masks, whh, bhh, outs, hbuf, flags, out + 1536);
  heads_k<<<128, 256, 0, stream>>>(outs, action, aw, ab, cw, cb, out);
}

// Round 10
// 807.390 us; speedup vs baseline: 1.4598x; 1.0968x over previous
//
#include <hip/hip_runtime.h>
#include <hip/hip_bf16.h>

// Problem constants
// inputs [512][4][124][124], conv1 w[32][4][8][8] s4 -> [512][32][30][30] (bf16 out)
// conv2 w[64][32][4][4] s2 -> [512][64][14][14]   (MFMA implicit GEMM)
// conv3 w[32][64][3][3] s1 -> [512][32][12][12] -> flat 4608
// fc [512,4608] -> xs [512][512] relu
// gi = xs @ w_ih^T + b_ih : [512][1536]
// GRU T=32, N=16, H=512 ; heads A=6
// d_out: value[512] | alp[512] | ent[512] | states_out[16*512]

typedef __bf16 bf16x8_t __attribute__((ext_vector_type(8)));
typedef float  f32x4_t  __attribute__((ext_vector_type(4)));

__device__ __forceinline__ unsigned int pack_bf2(float a, float b) {
  union { __bf16 h[2]; unsigned int u; } c;
  c.h[0] = (__bf16)a; c.h[1] = (__bf16)b;
  return c.u;
}
__device__ __forceinline__ unsigned short f2bf(float x) {
  union { __bf16 h; unsigned short s; } c; c.h = (__bf16)x; return c.s;
}

// ---------------- conv1 (fp32 compute, bf16 output) ----------------
__global__ __launch_bounds__(256) void conv1_k(const float* __restrict__ x,
        const float* __restrict__ w, const float* __restrict__ bias,
        unsigned short* __restrict__ out) {
  __shared__ float ws1[8192];               // [32 oc][4 c][8 ky][8 kx]
  for (int i = threadIdx.x; i < 2048; i += 256)
    ((float4*)ws1)[i] = ((const float4*)w)[i];
  __syncthreads();
  int pidx = blockIdx.x * 256 + threadIdx.x;   // [0, 512*450)
  int n = pidx / 450;
  int q = pidx % 450;
  int oy0 = q / 30, ox0 = q % 30;
  int q1 = q + 450;
  int oy1 = q1 / 30, ox1 = q1 % 30;
  float acc0[32], acc1[32];
  #pragma unroll
  for (int oc = 0; oc < 32; ++oc) { float bb = bias[oc] * 255.0f; acc0[oc] = bb; acc1[oc] = bb; }
  for (int c = 0; c < 4; ++c) {
    for (int ky = 0; ky < 8; ++ky) {
      const float* r0 = x + ((n*4 + c)*124 + oy0*4 + ky)*124 + ox0*4;
      const float* r1 = x + ((n*4 + c)*124 + oy1*4 + ky)*124 + ox1*4;
      float4 p0 = *(const float4*)r0, p1 = *(const float4*)(r0 + 4);
      float4 p2 = *(const float4*)r1, p3 = *(const float4*)(r1 + 4);
      float v0[8] = {p0.x,p0.y,p0.z,p0.w,p1.x,p1.y,p1.z,p1.w};
      float v1[8] = {p2.x,p2.y,p2.z,p2.w,p3.x,p3.y,p3.z,p3.w};
      const float* wb = &ws1[c*64 + ky*8];
      #pragma unroll
      for (int oc = 0; oc < 32; ++oc) {
        const float4* wr = (const float4*)(wb + oc*256);   // 16B-aligned
        float4 wa = wr[0], wc = wr[1];
        acc0[oc] += v0[0]*wa.x + v0[1]*wa.y + v0[2]*wa.z + v0[3]*wa.w
                  + v0[4]*wc.x + v0[5]*wc.y + v0[6]*wc.z + v0[7]*wc.w;
        acc1[oc] += v1[0]*wa.x + v1[1]*wa.y + v1[2]*wa.z + v1[3]*wa.w
                  + v1[4]*wc.x + v1[5]*wc.y + v1[6]*wc.z + v1[7]*wc.w;
      }
    }
  }
  const float sc = 1.0f / 255.0f;
  #pragma unroll
  for (int oc = 0; oc < 32; ++oc) {
    out[(n*32 + oc)*900 + q]       = f2bf(fmaxf(acc0[oc]*sc, 0.f));
    out[(n*32 + oc)*900 + q + 450] = f2bf(fmaxf(acc1[oc]*sc, 0.f));
  }
}

// ---------------- conv2: bf16 MFMA implicit GEMM (verified r9) ----------------
__global__ __launch_bounds__(256) void conv2_mfma(const unsigned short* __restrict__ in,
        const float* __restrict__ w, const float* __restrict__ bias,
        float* __restrict__ out) {
  __shared__ __align__(16) unsigned short pt[64*520];   // 65 KB
  const int tid  = threadIdx.x;
  const int lane = tid & 63;
  const int wv   = tid >> 6;
  const int px0  = blockIdx.x * 64;
  {
    int px = px0 + lane;
    int n = px / 196, q = px % 196;
    int oy = q / 14, ox = q % 14;
    const unsigned short* base = in + ((size_t)(n*32)*30 + oy*2)*30 + ox*2;
    #pragma unroll 4
    for (int it = 0; it < 32; ++it) {
      int c  = wv*8 + (it >> 2);
      int ky = it & 3;
      const unsigned short* src = base + (c*30 + ky)*30;
      unsigned int a0 = *(const unsigned int*)(src);
      unsigned int a1 = *(const unsigned int*)(src + 2);
      *(uint2*)&pt[lane*520 + c*16 + ky*4] = make_uint2(a0, a1);
    }
  }
  bf16x8_t wfr[16];
  {
    int m = lane & 15, q = lane >> 4;
    const float* wrow = w + (size_t)(wv*16 + m)*512 + q*8;
    #pragma unroll
    for (int ks = 0; ks < 16; ++ks) {
      float4 f0 = *(const float4*)(wrow + ks*32);
      float4 f1 = *(const float4*)(wrow + ks*32 + 4);
      bf16x8_t v;
      v[0] = (__bf16)f0.x; v[1] = (__bf16)f0.y; v[2] = (__bf16)f0.z; v[3] = (__bf16)f0.w;
      v[4] = (__bf16)f1.x; v[5] = (__bf16)f1.y; v[6] = (__bf16)f1.z; v[7] = (__bf16)f1.w;
      wfr[ks] = v;
    }
  }
  __syncthreads();
  f32x4_t acc[4];
  #pragma unroll
  for (int pxt = 0; pxt < 4; ++pxt) {
    f32x4_t a = {0.f, 0.f, 0.f, 0.f};
    const unsigned short* prow = &pt[(pxt*16 + (lane & 15))*520 + (lane >> 4)*8];
    #pragma unroll
    for (int ks = 0; ks < 16; ++ks) {
      union { bf16x8_t v; uint4 u; } fb;
      fb.u = *(const uint4*)(prow + ks*32);
      a = __builtin_amdgcn_mfma_f32_16x16x32_bf16(wfr[ks], fb.v, a, 0, 0, 0);
    }
    acc[pxt] = a;
  }
  {
    int q4 = lane >> 4;
    float b4[4];
    #pragma unroll
    for (int rg = 0; rg < 4; ++rg) b4[rg] = bias[wv*16 + q4*4 + rg];
    #pragma unroll
    for (int pxt = 0; pxt < 4; ++pxt) {
      int px = px0 + pxt*16 + (lane & 15);
      int n = px / 196, q = px % 196;
      #pragma unroll
      for (int rg = 0; rg < 4; ++rg) {
        int oc = wv*16 + q4*4 + rg;
        out[((size_t)n*64 + oc)*196 + q] = fmaxf(acc[pxt][rg] + b4[rg], 0.f);
      }
    }
  }
}

// ---------------- conv3 (r7 version, fp32) ----------------
__global__ __launch_bounds__(256) void conv3_k(const float* __restrict__ in,
        const float* __restrict__ w, const float* __restrict__ bias,
        float* __restrict__ out) {
  __shared__ float wsT[9216];               // [(c*3+ky)*3+kx][oc]
  int och0 = blockIdx.y * 16;
  for (int i = threadIdx.x; i < 9216; i += 256) {
    int oc = i & 15, rest = i >> 4;
    int kx = rest % 3, t2 = rest / 3;
    int ky = t2 % 3, c = t2 / 3;
    wsT[i] = w[(size_t)(och0 + oc)*576 + c*9 + ky*3 + kx];
  }
  __syncthreads();
  int pidx = blockIdx.x * 256 + threadIdx.x;   // [0, 512*72)
  int n = pidx / 72;
  int q = pidx % 72;
  int oy0 = q / 12, ox0 = q % 12;
  int q1 = q + 72;
  int oy1 = q1 / 12, ox1 = q1 % 12;
  float acc0[16], acc1[16];
  #pragma unroll
  for (int oc = 0; oc < 16; ++oc) { float bb = bias[och0 + oc]; acc0[oc] = bb; acc1[oc] = bb; }
  for (int c = 0; c < 64; ++c) {
    #pragma unroll
    for (int ky = 0; ky < 3; ++ky) {
      const float* r0 = in + ((n*64 + c)*14 + oy0 + ky)*14 + ox0;
      const float* r1 = in + ((n*64 + c)*14 + oy1 + ky)*14 + ox1;
      float v0[3] = {r0[0], r0[1], r0[2]};
      float v1[3] = {r1[0], r1[1], r1[2]};
      #pragma unroll
      for (int kx = 0; kx < 3; ++kx) {
        const float4* wp = (const float4*)&wsT[((c*3 + ky)*3 + kx)*16];
        float4 wA = wp[0], wB = wp[1], wC = wp[2], wD = wp[3];
        float a = v0[kx], b = v1[kx];
        acc0[0] += a*wA.x; acc0[1] += a*wA.y; acc0[2]  += a*wA.z; acc0[3]  += a*wA.w;
        acc0[4] += a*wB.x; acc0[5] += a*wB.y; acc0[6]  += a*wB.z; acc0[7]  += a*wB.w;
        acc0[8] += a*wC.x; acc0[9] += a*wC.y; acc0[10] += a*wC.z; acc0[11] += a*wC.w;
        acc0[12]+= a*wD.x; acc0[13]+= a*wD.y; acc0[14] += a*wD.z; acc0[15] += a*wD.w;
        acc1[0] += b*wA.x; acc1[1] += b*wA.y; acc1[2]  += b*wA.z; acc1[3]  += b*wA.w;
        acc1[4] += b*wB.x; acc1[5] += b*wB.y; acc1[6]  += b*wB.z; acc1[7]  += b*wB.w;
        acc1[8] += b*wC.x; acc1[9] += b*wC.y; acc1[10] += b*wC.z; acc1[11] += b*wC.w;
        acc1[12]+= b*wD.x; acc1[13]+= b*wD.y; acc1[14] += b*wD.z; acc1[15] += b*wD.w;
      }
    }
  }
  #pragma unroll
  for (int oc = 0; oc < 16; ++oc) {
    out[(n*32 + och0 + oc)*144 + q]      = fmaxf(acc0[oc], 0.f);
    out[(n*32 + och0 + oc)*144 + q + 72] = fmaxf(acc1[oc], 0.f);
  }
}

// ---------------- GEMM: C[M][N] = A[M][K] * B[N][K]^T + bias, optional ReLU ----------------
template<bool RELU>
__global__ __launch_bounds__(256) void gemm_k(const float* __restrict__ A, const float* __restrict__ B,
                                              const float* __restrict__ bias, float* __restrict__ C,
                                              int M, int N, int K) {
  __shared__ float As[32][33];
  __shared__ float Bs[32][33];
  const int tid = threadIdx.x;
  const int tx = tid & 15, ty = tid >> 4;
  const int m0 = blockIdx.y * 32, n0 = blockIdx.x * 32;
  const int lr = tid >> 3;        // 0..31
  const int lc = (tid & 7) * 4;   // 0..28
  float acc00 = 0.f, acc01 = 0.f, acc10 = 0.f, acc11 = 0.f;
  for (int k0 = 0; k0 < K; k0 += 32) {
    float4 a4 = *(const float4*)(A + (size_t)(m0 + lr)*K + k0 + lc);
    float4 b4 = *(const float4*)(B + (size_t)(n0 + lr)*K + k0 + lc);
    __syncthreads();
    As[lc+0][lr] = a4.x; As[lc+1][lr] = a4.y; As[lc+2][lr] = a4.z; As[lc+3][lr] = a4.w;
    Bs[lc+0][lr] = b4.x; Bs[lc+1][lr] = b4.y; Bs[lc+2][lr] = b4.z; Bs[lc+3][lr] = b4.w;
    __syncthreads();
    #pragma unroll
    for (int kk = 0; kk < 32; ++kk) {
      float a0 = As[kk][ty*2], a1 = As[kk][ty*2+1];
      float b0 = Bs[kk][tx*2], b1 = Bs[kk][tx*2+1];
      acc00 += a0*b0; acc01 += a0*b1; acc10 += a1*b0; acc11 += a1*b1;
    }
  }
  int m = m0 + ty*2, n = n0 + tx*2;
  float bi0 = bias[n], bi1 = bias[n+1];
  float c00 = acc00 + bi0, c01 = acc01 + bi1, c10 = acc10 + bi0, c11 = acc11 + bi1;
  if (RELU) {
    c00 = fmaxf(c00, 0.f); c01 = fmaxf(c01, 0.f);
    c10 = fmaxf(c10, 0.f); c11 = fmaxf(c11, 0.f);
  }
  C[(size_t)m*N + n] = c00;       C[(size_t)m*N + n + 1] = c01;
  C[(size_t)(m+1)*N + n] = c10;   C[(size_t)(m+1)*N + n + 1] = c11;
}

// ---------------- GRU persistent kernel (v8: fine-grained peer sync, no global barrier) ----------------
// 32 blocks x 256 threads, MFMA gh (r7-verified). No global barrier: block b
// posts flag[b]=t+1 after gates; at step t, wave w polls only its 8 peers'
// flags and gathers their 1 KB h-slices (hbuf layout [parity][peer][n][16j]).
// Own slice goes straight into LDS at gate time (no MALL round trip).
// Ping-pong parity safe: peer flag >= t+2 implies it finished reading parity A.
#define GRU_NB 32
__global__ __launch_bounds__(256) void gru_k(const float* __restrict__ gi, const float* __restrict__ states,
    const float* __restrict__ masks, const float* __restrict__ w_hh, const float* __restrict__ b_hh,
    float* __restrict__ outs, float* __restrict__ hbuf, int* __restrict__ flags,
    float* __restrict__ states_out) {
  __shared__ __align__(16) unsigned short hbf[16*516];  // h bf16, [n][516]
  __shared__ float hp_s[16*16];
  __shared__ float gh_s[48*17];
  __shared__ float bhs[48];
  __shared__ float mask_s[512];
  const int b    = blockIdx.x;
  const int tid  = threadIdx.x;
  const int lane = tid & 63;
  const int wv   = tid >> 6;
  const int jbase = b * 16;
  const int n2 = tid & 15;
  const int j2 = tid >> 4;

  for (int i = tid; i < 512; i += 256) mask_s[i] = masks[i];
  if (tid < 48) bhs[tid] = b_hh[(tid >> 4)*512 + jbase + (tid & 15)];

  bf16x8_t wfr[16];
  {
    int r = lane & 15, q = lane >> 4;
    int g = (wv < 3) ? wv : 0;
    const float* wrow = w_hh + (size_t)(g*512 + jbase + r)*512 + q*8;
    #pragma unroll
    for (int ks = 0; ks < 16; ++ks) {
      float4 f0 = *(const float4*)(wrow + ks*32);
      float4 f1 = *(const float4*)(wrow + ks*32 + 4);
      bf16x8_t v;
      v[0] = (__bf16)f0.x; v[1] = (__bf16)f0.y; v[2] = (__bf16)f0.z; v[3] = (__bf16)f0.w;
      v[4] = (__bf16)f1.x; v[5] = (__bf16)f1.y; v[6] = (__bf16)f1.z; v[7] = (__bf16)f1.w;
      wfr[ks] = v;
    }
  }
  __syncthreads();   // mask_s ready

  for (int t = 0; t < 32; ++t) {
    // ---- gi prefetch ----
    const float* gir_p = gi + (size_t)(t*16 + n2)*1536 + jbase + j2;
    float g_r = gir_p[0];
    float g_z = gir_p[512];
    float g_n = gir_p[1024];
    // ---- stage masked h (bf16) into LDS ----
    if (t == 0) {
      for (int i = tid; i < 4096; i += 256) {
        int nn = i >> 8, kp = (i & 255) * 2;
        float m = mask_s[nn];
        float f0 = states[nn*512 + kp], f1 = states[nn*512 + kp + 1];
        *(unsigned int*)&hbf[nn*516 + kp] = pack_bf2(f0*m, f1*m);
      }
      hp_s[n2*16 + j2] = states[n2*512 + jbase + j2] * mask_s[n2];
      __syncthreads();
    } else {
      // wave wv: poll its 8 peers, then gather their slices
      const int target = t;
      {
        int done = 0;
        while (!done) {
          int ok = 1;
          if (lane < 8) {
            int v = __hip_atomic_load(&flags[(wv*8 + lane)*16], __ATOMIC_RELAXED, __HIP_MEMORY_SCOPE_AGENT);
            ok = (v >= target);
          }
          done = __all(ok);
          if (!done) __builtin_amdgcn_s_sleep(1);
        }
      }
      {
        const float* hsrc = hbuf + (t & 1)*8192;
        int nn = lane >> 2;            // 0..15
        int j4 = (lane & 3) * 4;       // 0,4,8,12
        float m = mask_s[t*16 + nn];
        #pragma unroll
        for (int pi = 0; pi < 8; ++pi) {
          int p = wv*8 + pi;
          if (p == b) continue;        // own slice already in LDS (gate-time write)
          const unsigned long long* src =
              (const unsigned long long*)(hsrc + p*256 + nn*16 + j4);
          unsigned long long u0 = __hip_atomic_load(src,     __ATOMIC_RELAXED, __HIP_MEMORY_SCOPE_AGENT);
          unsigned long long u1 = __hip_atomic_load(src + 1, __ATOMIC_RELAXED, __HIP_MEMORY_SCOPE_AGENT);
          union { unsigned long long u; float f[2]; } a, c; a.u = u0; c.u = u1;
          uint2 wq;
          wq.x = pack_bf2(a.f[0]*m, a.f[1]*m);
          wq.y = pack_bf2(c.f[0]*m, c.f[1]*m);
          *(uint2*)&hbf[nn*516 + p*16 + j4] = wq;
        }
      }
      __syncthreads();
    }
    // ---- gh via MFMA: wave g computes gate-g 16x16 tile over K=512 ----
    if (wv < 3) {
      int r = lane & 15, q = lane >> 4;
      f32x4_t acc = {0.f, 0.f, 0.f, 0.f};
      const unsigned short* hrow = &hbf[r*516 + q*8];
      #pragma unroll
      for (int ks = 0; ks < 16; ++ks) {
        union { bf16x8_t v; uint2 u[2]; } fb;
        fb.u[0] = *(const uint2*)(hrow + ks*32);
        fb.u[1] = *(const uint2*)(hrow + ks*32 + 4);
        acc = __builtin_amdgcn_mfma_f32_16x16x32_bf16(wfr[ks], fb.v, acc, 0, 0, 0);
      }
      #pragma unroll
      for (int rg = 0; rg < 4; ++rg)
        gh_s[(wv*16 + q*4 + rg)*17 + r] = acc[rg];
    }
    __syncthreads();
    // ---- gates ----
    {
      float ghr = gh_s[(j2)*17 + n2]      + bhs[j2];
      float ghz = gh_s[(16 + j2)*17 + n2] + bhs[16 + j2];
      float ghn = gh_s[(32 + j2)*17 + n2] + bhs[32 + j2];
      float rg = 1.f / (1.f + expf(-(g_r + ghr)));
      float zg = 1.f / (1.f + expf(-(g_z + ghz)));
      float ng = tanhf(g_n + rg*ghn);
      float hp = hp_s[n2*16 + j2];
      float hn = (1.f - zg)*ng + zg*hp;
      outs[(size_t)(t*16 + n2)*512 + jbase + j2] = hn;
      if (t < 31) {
        // raw h for peers (they apply their own mask)
        __hip_atomic_store(hbuf + ((t+1)&1)*8192 + b*256 + n2*16 + j2, hn,
                           __ATOMIC_RELAXED, __HIP_MEMORY_SCOPE_AGENT);
        float hm = hn * mask_s[(t+1)*16 + n2];
        hp_s[n2*16 + j2] = hm;
        hbf[n2*516 + jbase + j2] = f2bf(hm);   // own slice straight into LDS
      } else {
        states_out[n2*512 + jbase + j2] = hn;
      }
    }
    // ---- post flag (no global barrier) ----
    if (t < 31) {
      __syncthreads();   // drains all h stores (vmcnt 0) + hbf own-slice writes
      if (tid == 0)
        __hip_atomic_store(&flags[b*16], t + 1, __ATOMIC_RELAXED, __HIP_MEMORY_SCOPE_AGENT);
    }
  }
}

// ---------------- heads ----------------
__global__ __launch_bounds__(256) void heads_k(const float* __restrict__ xs, const int* __restrict__ action,
    const float* __restrict__ aw, const float* __restrict__ ab,
    const float* __restrict__ cw, const float* __restrict__ cb, float* __restrict__ out) {
  int row  = blockIdx.x * 4 + (threadIdx.x >> 6);
  int lane = threadIdx.x & 63;
  const float* xr = xs + (size_t)row * 512;
  float acc[7];
  #pragma unroll
  for (int a = 0; a < 7; ++a) acc[a] = 0.f;
  #pragma unroll
  for (int kb = 0; kb < 8; ++kb) {
    int k = kb*64 + lane;
    float xv = xr[k];
    #pragma unroll
    for (int a = 0; a < 6; ++a) acc[a] += xv * aw[a*512 + k];
    acc[6] += xv * cw[k];
  }
  #pragma unroll
  for (int off = 32; off > 0; off >>= 1) {
    #pragma unroll
    for (int a = 0; a < 7; ++a) acc[a] += __shfl_down(acc[a], off);
  }
  if (lane == 0) {
    float lg[6];
    #pragma unroll
    for (int a = 0; a < 6; ++a) lg[a] = acc[a] + ab[a];
    float mx = lg[0];
    #pragma unroll
    for (int a = 1; a < 6; ++a) mx = fmaxf(mx, lg[a]);
    float se = 0.f;
    #pragma unroll
    for (int a = 0; a < 6; ++a) se += expf(lg[a] - mx);
    float lse = mx + logf(se);
    float ent = 0.f;
    #pragma unroll
    for (int a = 0; a < 6; ++a) { float lp = lg[a] - lse; ent -= expf(lp)*lp; }
    int ai = action[row];
    out[row]        = acc[6] + cb[0];
    out[512  + row] = lg[ai] - lse;
    out[1024 + row] = ent;
  }
}

extern "C" void kernel_launch(void* const* d_in, const int* in_sizes, int n_in,
                              void* d_out, int out_size, void* d_ws, size_t ws_size,
                              hipStream_t stream) {
  const float* x      = (const float*)d_in[0];
  const float* states = (const float*)d_in[1];
  const float* masks  = (const float*)d_in[2];
  const int*   action = (const int*)d_in[3];
  const float* c1w = (const float*)d_in[4];
  const float* c1b = (const float*)d_in[5];
  const float* c2w = (const float*)d_in[6];
  const float* c2b = (const float*)d_in[7];
  const float* c3w = (const float*)d_in[8];
  const float* c3b = (const float*)d_in[9];
  const float* fcw = (const float*)d_in[10];
  const float* fcb = (const float*)d_in[11];
  const float* wih = (const float*)d_in[12];
  const float* whh = (const float*)d_in[13];
  const float* bih = (const float*)d_in[14];
  const float* bhh = (const float*)d_in[15];
  const float* aw  = (const float*)d_in[16];
  const float* ab  = (const float*)d_in[17];
  const float* cw  = (const float*)d_in[18];
  const float* cb  = (const float*)d_in[19];
  (void)in_sizes; (void)n_in; (void)out_size; (void)ws_size;

  float* ws = (float*)d_ws;
  unsigned short* o1b = (unsigned short*)ws;     // bf16, 14.7M ushorts
  float* o2    = ws + 14745600;
  float* o3    = ws;                             // reused after conv2 consumed o1b
  float* xs    = ws + 2359296;
  float* gibuf = ws + 2621440;
  float* outs  = ws + 3407872;
  float* hbuf  = ws + 3670016;
  int*   flags = (int*)(ws + 3686400);
  float* out   = (float*)d_out;

  conv1_k<<<900, 256, 0, stream>>>(x, c1w, c1b, o1b);
  conv2_mfma<<<1568, 256, 0, stream>>>(o1b, c2w, c2b, o2);
  conv3_k<<<dim3(144, 2), 256, 0, stream>>>(o2, c3w, c3b, o3);
  gemm_k<true ><<<dim3(16, 16), 256, 0, stream>>>(o3, fcw, fcb, xs, 512, 512, 4608);
  gemm_k<false><<<dim3(48, 16), 256, 0, stream>>>(xs, wih, bih, gibuf, 512, 1536, 512);
  hipMemsetAsync(flags, 0, 1024 * sizeof(int), stream);
  gru_k<<<GRU_NB, 256, 0, stream>>>(gibuf, states, masks, whh, bhh, outs, hbuf, flags, out + 1536);
  heads_k<<<128, 256, 0, stream>>>(outs, action, aw, ab, cw, cb, out);
}

// Round 11
// 720.800 us; speedup vs baseline: 1.6351x; 1.1201x over previous
//
#include <hip/hip_runtime.h>
#include <hip/hip_bf16.h>

// Problem constants
// inputs [512][4][124][124], conv1 w[32][4][8][8] s4 -> [512][32][30][30] (bf16, MFMA)
// conv2 w[64][32][4][4] s2 -> [512][64][14][14]   (MFMA implicit GEMM)
// conv3 w[32][64][3][3] s1 -> [512][32][12][12] bf16 -> flat 4608
// fc [512,4608] -> xs [512][512] relu  (MFMA)
// gi = xs @ w_ih^T + b_ih : [512][1536]
// GRU T=32, N=16, H=512 ; heads A=6
// d_out: value[512] | alp[512] | ent[512] | states_out[16*512]

typedef __bf16 bf16x8_t __attribute__((ext_vector_type(8)));
typedef float  f32x4_t  __attribute__((ext_vector_type(4)));

__device__ __forceinline__ unsigned int pack_bf2(float a, float b) {
  union { __bf16 h[2]; unsigned int u; } c;
  c.h[0] = (__bf16)a; c.h[1] = (__bf16)b;
  return c.u;
}
__device__ __forceinline__ unsigned short f2bf(float x) {
  union { __bf16 h; unsigned short s; } c; c.h = (__bf16)x; return c.s;
}

// ---------------- conv1: bf16 MFMA implicit GEMM ----------------
// M = 512*900 px, N = 32 oc, K = 4c*8ky*8kx = 256. 7200 blocks x 256 thr.
// Wave wv stages channel c=wv for all 64 px; computes px-tile [16wv,16wv+16)
// over both oc-tiles. Weights = 2x8 A-frags in regs (r7/r9-proven layout).
__global__ __launch_bounds__(256) void conv1_mfma(const float* __restrict__ x,
        const float* __restrict__ w, const float* __restrict__ bias,
        unsigned short* __restrict__ out) {
  __shared__ __align__(16) unsigned short pt[64*264];   // 33.8 KB, K=256 pad->264
  const int tid  = threadIdx.x;
  const int lane = tid & 63;
  const int wv   = tid >> 6;
  const int px0  = blockIdx.x * 64;
  // ---- staging: lane = px-local; wave wv = channel wv ----
  {
    int px = px0 + lane;
    int n = px / 900, q = px % 900;
    int oy = q / 30, ox = q % 30;
    const float* base = x + ((size_t)(n*4 + wv)*124 + oy*4)*124 + ox*4;  // 16B-aligned (124%4==0)
    #pragma unroll
    for (int ky = 0; ky < 8; ++ky) {
      const float* src = base + ky*124;
      float4 f0 = *(const float4*)src;
      float4 f1 = *(const float4*)(src + 4);
      uint4 v;
      v.x = pack_bf2(f0.x, f0.y); v.y = pack_bf2(f0.z, f0.w);
      v.z = pack_bf2(f1.x, f1.y); v.w = pack_bf2(f1.z, f1.w);
      *(uint4*)&pt[lane*264 + wv*64 + ky*8] = v;
    }
  }
  // ---- weights -> A-frags (2 oc-tiles x 8 ksteps) ----
  bf16x8_t wfr[2][8];
  {
    int m = lane & 15, q = lane >> 4;
    #pragma unroll
    for (int tt = 0; tt < 2; ++tt) {
      const float* wrow = w + (size_t)(tt*16 + m)*256 + q*8;
      #pragma unroll
      for (int ks = 0; ks < 8; ++ks) {
        float4 f0 = *(const float4*)(wrow + ks*32);
        float4 f1 = *(const float4*)(wrow + ks*32 + 4);
        bf16x8_t v;
        v[0]=(__bf16)f0.x; v[1]=(__bf16)f0.y; v[2]=(__bf16)f0.z; v[3]=(__bf16)f0.w;
        v[4]=(__bf16)f1.x; v[5]=(__bf16)f1.y; v[6]=(__bf16)f1.z; v[7]=(__bf16)f1.w;
        wfr[tt][ks] = v;
      }
    }
  }
  __syncthreads();
  // ---- MFMA: wave wv -> px-tile wv, both oc-tiles ----
  f32x4_t acc0 = {0.f,0.f,0.f,0.f}, acc1 = {0.f,0.f,0.f,0.f};
  {
    const unsigned short* prow = &pt[(wv*16 + (lane & 15))*264 + (lane >> 4)*8];
    #pragma unroll
    for (int ks = 0; ks < 8; ++ks) {
      union { bf16x8_t v; uint4 u; } fb;
      fb.u = *(const uint4*)(prow + ks*32);
      acc0 = __builtin_amdgcn_mfma_f32_16x16x32_bf16(wfr[0][ks], fb.v, acc0, 0, 0, 0);
      acc1 = __builtin_amdgcn_mfma_f32_16x16x32_bf16(wfr[1][ks], fb.v, acc1, 0, 0, 0);
    }
  }
  // ---- epilogue: col = px-local, row = oc-local ----
  {
    int q4 = lane >> 4;
    int px = px0 + wv*16 + (lane & 15);
    int n = px / 900, q = px % 900;
    const float sc = 1.0f / 255.0f;
    #pragma unroll
    for (int rg = 0; rg < 4; ++rg) {
      int oc0 = q4*4 + rg;
      out[((size_t)n*32 + oc0)*900 + q]      = f2bf(fmaxf(acc0[rg]*sc + bias[oc0], 0.f));
      out[((size_t)n*32 + oc0 + 16)*900 + q] = f2bf(fmaxf(acc1[rg]*sc + bias[oc0 + 16], 0.f));
    }
  }
}

// ---------------- conv2: bf16 MFMA implicit GEMM (verified r9) ----------------
__global__ __launch_bounds__(256) void conv2_mfma(const unsigned short* __restrict__ in,
        const float* __restrict__ w, const float* __restrict__ bias,
        float* __restrict__ out) {
  __shared__ __align__(16) unsigned short pt[64*520];   // 65 KB
  const int tid  = threadIdx.x;
  const int lane = tid & 63;
  const int wv   = tid >> 6;
  const int px0  = blockIdx.x * 64;
  {
    int px = px0 + lane;
    int n = px / 196, q = px % 196;
    int oy = q / 14, ox = q % 14;
    const unsigned short* base = in + ((size_t)(n*32)*30 + oy*2)*30 + ox*2;
    #pragma unroll 4
    for (int it = 0; it < 32; ++it) {
      int c  = wv*8 + (it >> 2);
      int ky = it & 3;
      const unsigned short* src = base + (c*30 + ky)*30;
      unsigned int a0 = *(const unsigned int*)(src);
      unsigned int a1 = *(const unsigned int*)(src + 2);
      *(uint2*)&pt[lane*520 + c*16 + ky*4] = make_uint2(a0, a1);
    }
  }
  bf16x8_t wfr[16];
  {
    int m = lane & 15, q = lane >> 4;
    const float* wrow = w + (size_t)(wv*16 + m)*512 + q*8;
    #pragma unroll
    for (int ks = 0; ks < 16; ++ks) {
      float4 f0 = *(const float4*)(wrow + ks*32);
      float4 f1 = *(const float4*)(wrow + ks*32 + 4);
      bf16x8_t v;
      v[0] = (__bf16)f0.x; v[1] = (__bf16)f0.y; v[2] = (__bf16)f0.z; v[3] = (__bf16)f0.w;
      v[4] = (__bf16)f1.x; v[5] = (__bf16)f1.y; v[6] = (__bf16)f1.z; v[7] = (__bf16)f1.w;
      wfr[ks] = v;
    }
  }
  __syncthreads();
  f32x4_t acc[4];
  #pragma unroll
  for (int pxt = 0; pxt < 4; ++pxt) {
    f32x4_t a = {0.f, 0.f, 0.f, 0.f};
    const unsigned short* prow = &pt[(pxt*16 + (lane & 15))*520 + (lane >> 4)*8];
    #pragma unroll
    for (int ks = 0; ks < 16; ++ks) {
      union { bf16x8_t v; uint4 u; } fb;
      fb.u = *(const uint4*)(prow + ks*32);
      a = __builtin_amdgcn_mfma_f32_16x16x32_bf16(wfr[ks], fb.v, a, 0, 0, 0);
    }
    acc[pxt] = a;
  }
  {
    int q4 = lane >> 4;
    float b4[4];
    #pragma unroll
    for (int rg = 0; rg < 4; ++rg) b4[rg] = bias[wv*16 + q4*4 + rg];
    #pragma unroll
    for (int pxt = 0; pxt < 4; ++pxt) {
      int px = px0 + pxt*16 + (lane & 15);
      int n = px / 196, q = px % 196;
      #pragma unroll
      for (int rg = 0; rg < 4; ++rg) {
        int oc = wv*16 + q4*4 + rg;
        out[((size_t)n*64 + oc)*196 + q] = fmaxf(acc[pxt][rg] + b4[rg], 0.f);
      }
    }
  }
}

// ---------------- conv3 (fp32 compute, bf16 output for fc MFMA) ----------------
__global__ __launch_bounds__(256) void conv3_k(const float* __restrict__ in,
        const float* __restrict__ w, const float* __restrict__ bias,
        unsigned short* __restrict__ out) {
  __shared__ float wsT[9216];               // [(c*3+ky)*3+kx][oc]
  int och0 = blockIdx.y * 16;
  for (int i = threadIdx.x; i < 9216; i += 256) {
    int oc = i & 15, rest = i >> 4;
    int kx = rest % 3, t2 = rest / 3;
    int ky = t2 % 3, c = t2 / 3;
    wsT[i] = w[(size_t)(och0 + oc)*576 + c*9 + ky*3 + kx];
  }
  __syncthreads();
  int pidx = blockIdx.x * 256 + threadIdx.x;   // [0, 512*72)
  int n = pidx / 72;
  int q = pidx % 72;
  int oy0 = q / 12, ox0 = q % 12;
  int q1 = q + 72;
  int oy1 = q1 / 12, ox1 = q1 % 12;
  float acc0[16], acc1[16];
  #pragma unroll
  for (int oc = 0; oc < 16; ++oc) { float bb = bias[och0 + oc]; acc0[oc] = bb; acc1[oc] = bb; }
  for (int c = 0; c < 64; ++c) {
    #pragma unroll
    for (int ky = 0; ky < 3; ++ky) {
      const float* r0 = in + ((n*64 + c)*14 + oy0 + ky)*14 + ox0;
      const float* r1 = in + ((n*64 + c)*14 + oy1 + ky)*14 + ox1;
      float v0[3] = {r0[0], r0[1], r0[2]};
      float v1[3] = {r1[0], r1[1], r1[2]};
      #pragma unroll
      for (int kx = 0; kx < 3; ++kx) {
        const float4* wp = (const float4*)&wsT[((c*3 + ky)*3 + kx)*16];
        float4 wA = wp[0], wB = wp[1], wC = wp[2], wD = wp[3];
        float a = v0[kx], b = v1[kx];
        acc0[0] += a*wA.x; acc0[1] += a*wA.y; acc0[2]  += a*wA.z; acc0[3]  += a*wA.w;
        acc0[4] += a*wB.x; acc0[5] += a*wB.y; acc0[6]  += a*wB.z; acc0[7]  += a*wB.w;
        acc0[8] += a*wC.x; acc0[9] += a*wC.y; acc0[10] += a*wC.z; acc0[11] += a*wC.w;
        acc0[12]+= a*wD.x; acc0[13]+= a*wD.y; acc0[14] += a*wD.z; acc0[15] += a*wD.w;
        acc1[0] += b*wA.x; acc1[1] += b*wA.y; acc1[2]  += b*wA.z; acc1[3]  += b*wA.w;
        acc1[4] += b*wB.x; acc1[5] += b*wB.y; acc1[6]  += b*wB.z; acc1[7]  += b*wB.w;
        acc1[8] += b*wC.x; acc1[9] += b*wC.y; acc1[10] += b*wC.z; acc1[11] += b*wC.w;
        acc1[12]+= b*wD.x; acc1[13]+= b*wD.y; acc1[14] += b*wD.z; acc1[15] += b*wD.w;
      }
    }
  }
  #pragma unroll
  for (int oc = 0; oc < 16; ++oc) {
    out[(n*32 + och0 + oc)*144 + q]      = f2bf(fmaxf(acc0[oc], 0.f));
    out[(n*32 + och0 + oc)*144 + q + 72] = f2bf(fmaxf(acc1[oc], 0.f));
  }
}

// ---------------- fc: bf16 MFMA GEMM ----------------
// xs[512][512] = relu(A[512][4608](bf16) x W[512][4608]^T + bias).
// Grid (8,8): 64x64 tile. LDS: A-tile + W-tile 64x(64+8) bf16, K chunks of 64.
__global__ __launch_bounds__(256) void fc_mfma(const unsigned short* __restrict__ A,
        const float* __restrict__ W, const float* __restrict__ bias,
        float* __restrict__ C) {
  __shared__ __align__(16) unsigned short As[64*72];
  __shared__ __align__(16) unsigned short Wsm[64*72];
  const int tid  = threadIdx.x;
  const int lane = tid & 63;
  const int wv   = tid >> 6;
  const int m0 = blockIdx.y * 64, n0 = blockIdx.x * 64;
  const int r  = tid >> 2;
  const int cq = (tid & 3) * 16;
  f32x4_t acc[4] = {{0,0,0,0},{0,0,0,0},{0,0,0,0},{0,0,0,0}};
  for (int k0 = 0; k0 < 4608; k0 += 64) {
    __syncthreads();   // WAR vs previous chunk's reads
    {
      const uint4* src = (const uint4*)(A + (size_t)(m0 + r)*4608 + k0 + cq);
      uint4 a0 = src[0], a1 = src[1];
      *(uint4*)&As[r*72 + cq]     = a0;
      *(uint4*)&As[r*72 + cq + 8] = a1;
    }
    {
      const float* src = W + (size_t)(n0 + r)*4608 + k0 + cq;
      float4 f0 = *(const float4*)src,       f1 = *(const float4*)(src + 4);
      float4 f2 = *(const float4*)(src + 8), f3 = *(const float4*)(src + 12);
      uint4 v0, v1;
      v0.x = pack_bf2(f0.x,f0.y); v0.y = pack_bf2(f0.z,f0.w);
      v0.z = pack_bf2(f1.x,f1.y); v0.w = pack_bf2(f1.z,f1.w);
      v1.x = pack_bf2(f2.x,f2.y); v1.y = pack_bf2(f2.z,f2.w);
      v1.z = pack_bf2(f3.x,f3.y); v1.w = pack_bf2(f3.z,f3.w);
      *(uint4*)&Wsm[r*72 + cq]     = v0;
      *(uint4*)&Wsm[r*72 + cq + 8] = v1;
    }
    __syncthreads();
    #pragma unroll
    for (int kk = 0; kk < 2; ++kk) {
      union { bf16x8_t v; uint4 u; } bf;
      bf.u = *(const uint4*)&As[(wv*16 + (lane & 15))*72 + kk*32 + (lane >> 4)*8];
      #pragma unroll
      for (int tt = 0; tt < 4; ++tt) {
        union { bf16x8_t v; uint4 u; } af;
        af.u = *(const uint4*)&Wsm[(tt*16 + (lane & 15))*72 + kk*32 + (lane >> 4)*8];
        acc[tt] = __builtin_amdgcn_mfma_f32_16x16x32_bf16(af.v, bf.v, acc[tt], 0, 0, 0);
      }
    }
  }
  {
    int m = m0 + wv*16 + (lane & 15);
    int q4 = lane >> 4;
    #pragma unroll
    for (int tt = 0; tt < 4; ++tt) {
      #pragma unroll
      for (int rg = 0; rg < 4; ++rg) {
        int n = n0 + tt*16 + q4*4 + rg;
        C[(size_t)m*512 + n] = fmaxf(acc[tt][rg] + bias[n], 0.f);
      }
    }
  }
}

// ---------------- GEMM fp32 (gi only): C[M][N] = A*B^T + bias ----------------
template<bool RELU>
__global__ __launch_bounds__(256) void gemm_k(const float* __restrict__ A, const float* __restrict__ B,
                                              const float* __restrict__ bias, float* __restrict__ C,
                                              int M, int N, int K) {
  __shared__ float As[32][33];
  __shared__ float Bs[32][33];
  const int tid = threadIdx.x;
  const int tx = tid & 15, ty = tid >> 4;
  const int m0 = blockIdx.y * 32, n0 = blockIdx.x * 32;
  const int lr = tid >> 3;
  const int lc = (tid & 7) * 4;
  float acc00 = 0.f, acc01 = 0.f, acc10 = 0.f, acc11 = 0.f;
  for (int k0 = 0; k0 < K; k0 += 32) {
    float4 a4 = *(const float4*)(A + (size_t)(m0 + lr)*K + k0 + lc);
    float4 b4 = *(const float4*)(B + (size_t)(n0 + lr)*K + k0 + lc);
    __syncthreads();
    As[lc+0][lr] = a4.x; As[lc+1][lr] = a4.y; As[lc+2][lr] = a4.z; As[lc+3][lr] = a4.w;
    Bs[lc+0][lr] = b4.x; Bs[lc+1][lr] = b4.y; Bs[lc+2][lr] = b4.z; Bs[lc+3][lr] = b4.w;
    __syncthreads();
    #pragma unroll
    for (int kk = 0; kk < 32; ++kk) {
      float a0 = As[kk][ty*2], a1 = As[kk][ty*2+1];
      float b0 = Bs[kk][tx*2], b1 = Bs[kk][tx*2+1];
      acc00 += a0*b0; acc01 += a0*b1; acc10 += a1*b0; acc11 += a1*b1;
    }
  }
  int m = m0 + ty*2, n = n0 + tx*2;
  float bi0 = bias[n], bi1 = bias[n+1];
  float c00 = acc00 + bi0, c01 = acc01 + bi1, c10 = acc10 + bi0, c11 = acc11 + bi1;
  if (RELU) {
    c00 = fmaxf(c00, 0.f); c01 = fmaxf(c01, 0.f);
    c10 = fmaxf(c10, 0.f); c11 = fmaxf(c11, 0.f);
  }
  C[(size_t)m*N + n] = c00;       C[(size_t)m*N + n + 1] = c01;
  C[(size_t)(m+1)*N + n] = c10;   C[(size_t)(m+1)*N + n + 1] = c11;
}

// ---------------- GRU persistent kernel (v8: fine-grained peer sync, verified r10) ----------------
#define GRU_NB 32
__global__ __launch_bounds__(256) void gru_k(const float* __restrict__ gi, const float* __restrict__ states,
    const float* __restrict__ masks, const float* __restrict__ w_hh, const float* __restrict__ b_hh,
    float* __restrict__ outs, float* __restrict__ hbuf, int* __restrict__ flags,
    float* __restrict__ states_out) {
  __shared__ __align__(16) unsigned short hbf[16*516];
  __shared__ float hp_s[16*16];
  __shared__ float gh_s[48*17];
  __shared__ float bhs[48];
  __shared__ float mask_s[512];
  const int b    = blockIdx.x;
  const int tid  = threadIdx.x;
  const int lane = tid & 63;
  const int wv   = tid >> 6;
  const int jbase = b * 16;
  const int n2 = tid & 15;
  const int j2 = tid >> 4;

  for (int i = tid; i < 512; i += 256) mask_s[i] = masks[i];
  if (tid < 48) bhs[tid] = b_hh[(tid >> 4)*512 + jbase + (tid & 15)];

  bf16x8_t wfr[16];
  {
    int r = lane & 15, q = lane >> 4;
    int g = (wv < 3) ? wv : 0;
    const float* wrow = w_hh + (size_t)(g*512 + jbase + r)*512 + q*8;
    #pragma unroll
    for (int ks = 0; ks < 16; ++ks) {
      float4 f0 = *(const float4*)(wrow + ks*32);
      float4 f1 = *(const float4*)(wrow + ks*32 + 4);
      bf16x8_t v;
      v[0] = (__bf16)f0.x; v[1] = (__bf16)f0.y; v[2] = (__bf16)f0.z; v[3] = (__bf16)f0.w;
      v[4] = (__bf16)f1.x; v[5] = (__bf16)f1.y; v[6] = (__bf16)f1.z; v[7] = (__bf16)f1.w;
      wfr[ks] = v;
    }
  }
  __syncthreads();

  for (int t = 0; t < 32; ++t) {
    const float* gir_p = gi + (size_t)(t*16 + n2)*1536 + jbase + j2;
    float g_r = gir_p[0];
    float g_z = gir_p[512];
    float g_n = gir_p[1024];
    if (t == 0) {
      for (int i = tid; i < 4096; i += 256) {
        int nn = i >> 8, kp = (i & 255) * 2;
        float m = mask_s[nn];
        float f0 = states[nn*512 + kp], f1 = states[nn*512 + kp + 1];
        *(unsigned int*)&hbf[nn*516 + kp] = pack_bf2(f0*m, f1*m);
      }
      hp_s[n2*16 + j2] = states[n2*512 + jbase + j2] * mask_s[n2];
      __syncthreads();
    } else {
      const int target = t;
      {
        int done = 0;
        while (!done) {
          int ok = 1;
          if (lane < 8) {
            int v = __hip_atomic_load(&flags[(wv*8 + lane)*16], __ATOMIC_RELAXED, __HIP_MEMORY_SCOPE_AGENT);
            ok = (v >= target);
          }
          done = __all(ok);
          if (!done) __builtin_amdgcn_s_sleep(1);
        }
      }
      {
        const float* hsrc = hbuf + (t & 1)*8192;
        int nn = lane >> 2;
        int j4 = (lane & 3) * 4;
        float m = mask_s[t*16 + nn];
        #pragma unroll
        for (int pi = 0; pi < 8; ++pi) {
          int p = wv*8 + pi;
          if (p == b) continue;
          const unsigned long long* src =
              (const unsigned long long*)(hsrc + p*256 + nn*16 + j4);
          unsigned long long u0 = __hip_atomic_load(src,     __ATOMIC_RELAXED, __HIP_MEMORY_SCOPE_AGENT);
          unsigned long long u1 = __hip_atomic_load(src + 1, __ATOMIC_RELAXED, __HIP_MEMORY_SCOPE_AGENT);
          union { unsigned long long u; float f[2]; } a, c; a.u = u0; c.u = u1;
          uint2 wq;
          wq.x = pack_bf2(a.f[0]*m, a.f[1]*m);
          wq.y = pack_bf2(c.f[0]*m, c.f[1]*m);
          *(uint2*)&hbf[nn*516 + p*16 + j4] = wq;
        }
      }
      __syncthreads();
    }
    if (wv < 3) {
      int r = lane & 15, q = lane >> 4;
      f32x4_t acc = {0.f, 0.f, 0.f, 0.f};
      const unsigned short* hrow = &hbf[r*516 + q*8];
      #pragma unroll
      for (int ks = 0; ks < 16; ++ks) {
        union { bf16x8_t v; uint2 u[2]; } fb;
        fb.u[0] = *(const uint2*)(hrow + ks*32);
        fb.u[1] = *(const uint2*)(hrow + ks*32 + 4);
        acc = __builtin_amdgcn_mfma_f32_16x16x32_bf16(wfr[ks], fb.v, acc, 0, 0, 0);
      }
      #pragma unroll
      for (int rg = 0; rg < 4; ++rg)
        gh_s[(wv*16 + q*4 + rg)*17 + r] = acc[rg];
    }
    __syncthreads();
    {
      float ghr = gh_s[(j2)*17 + n2]      + bhs[j2];
      float ghz = gh_s[(16 + j2)*17 + n2] + bhs[16 + j2];
      float ghn = gh_s[(32 + j2)*17 + n2] + bhs[32 + j2];
      float rg = 1.f / (1.f + expf(-(g_r + ghr)));
      float zg = 1.f / (1.f + expf(-(g_z + ghz)));
      float ng = tanhf(g_n + rg*ghn);
      float hp = hp_s[n2*16 + j2];
      float hn = (1.f - zg)*ng + zg*hp;
      outs[(size_t)(t*16 + n2)*512 + jbase + j2] = hn;
      if (t < 31) {
        __hip_atomic_store(hbuf + ((t+1)&1)*8192 + b*256 + n2*16 + j2, hn,
                           __ATOMIC_RELAXED, __HIP_MEMORY_SCOPE_AGENT);
        float hm = hn * mask_s[(t+1)*16 + n2];
        hp_s[n2*16 + j2] = hm;
        hbf[n2*516 + jbase + j2] = f2bf(hm);
      } else {
        states_out[n2*512 + jbase + j2] = hn;
      }
    }
    if (t < 31) {
      __syncthreads();
      if (tid == 0)
        __hip_atomic_store(&flags[b*16], t + 1, __ATOMIC_RELAXED, __HIP_MEMORY_SCOPE_AGENT);
    }
  }
}

// ---------------- heads ----------------
__global__ __launch_bounds__(256) void heads_k(const float* __restrict__ xs, const int* __restrict__ action,
    const float* __restrict__ aw, const float* __restrict__ ab,
    const float* __restrict__ cw, const float* __restrict__ cb, float* __restrict__ out) {
  int row  = blockIdx.x * 4 + (threadIdx.x >> 6);
  int lane = threadIdx.x & 63;
  const float* xr = xs + (size_t)row * 512;
  float acc[7];
  #pragma unroll
  for (int a = 0; a < 7; ++a) acc[a] = 0.f;
  #pragma unroll
  for (int kb = 0; kb < 8; ++kb) {
    int k = kb*64 + lane;
    float xv = xr[k];
    #pragma unroll
    for (int a = 0; a < 6; ++a) acc[a] += xv * aw[a*512 + k];
    acc[6] += xv * cw[k];
  }
  #pragma unroll
  for (int off = 32; off > 0; off >>= 1) {
    #pragma unroll
    for (int a = 0; a < 7; ++a) acc[a] += __shfl_down(acc[a], off);
  }
  if (lane == 0) {
    float lg[6];
    #pragma unroll
    for (int a = 0; a < 6; ++a) lg[a] = acc[a] + ab[a];
    float mx = lg[0];
    #pragma unroll
    for (int a = 1; a < 6; ++a) mx = fmaxf(mx, lg[a]);
    float se = 0.f;
    #pragma unroll
    for (int a = 0; a < 6; ++a) se += expf(lg[a] - mx);
    float lse = mx + logf(se);
    float ent = 0.f;
    #pragma unroll
    for (int a = 0; a < 6; ++a) { float lp = lg[a] - lse; ent -= expf(lp)*lp; }
    int ai = action[row];
    out[row]        = acc[6] + cb[0];
    out[512  + row] = lg[ai] - lse;
    out[1024 + row] = ent;
  }
}

extern "C" void kernel_launch(void* const* d_in, const int* in_sizes, int n_in,
                              void* d_out, int out_size, void* d_ws, size_t ws_size,
                              hipStream_t stream) {
  const float* x      = (const float*)d_in[0];
  const float* states = (const float*)d_in[1];
  const float* masks  = (const float*)d_in[2];
  const int*   action = (const int*)d_in[3];
  const float* c1w = (const float*)d_in[4];
  const float* c1b = (const float*)d_in[5];
  const float* c2w = (const float*)d_in[6];
  const float* c2b = (const float*)d_in[7];
  const float* c3w = (const float*)d_in[8];
  const float* c3b = (const float*)d_in[9];
  const float* fcw = (const float*)d_in[10];
  const float* fcb = (const float*)d_in[11];
  const float* wih = (const float*)d_in[12];
  const float* whh = (const float*)d_in[13];
  const float* bih = (const float*)d_in[14];
  const float* bhh = (const float*)d_in[15];
  const float* aw  = (const float*)d_in[16];
  const float* ab  = (const float*)d_in[17];
  const float* cw  = (const float*)d_in[18];
  const float* cb  = (const float*)d_in[19];
  (void)in_sizes; (void)n_in; (void)out_size; (void)ws_size;

  float* ws = (float*)d_ws;
  unsigned short* o1b = (unsigned short*)ws;     // conv1 out bf16
  float* o2    = ws + 14745600;                  // conv2 out fp32
  unsigned short* o3b = (unsigned short*)ws;     // conv3 out bf16 (reuses o1b region after conv2)
  float* xs    = ws + 2359296;
  float* gibuf = ws + 2621440;
  float* outs  = ws + 3407872;
  float* hbuf  = ws + 3670016;
  int*   flags = (int*)(ws + 3686400);
  float* out   = (float*)d_out;

  conv1_mfma<<<7200, 256, 0, stream>>>(x, c1w, c1b, o1b);
  conv2_mfma<<<1568, 256, 0, stream>>>(o1b, c2w, c2b, o2);
  conv3_k<<<dim3(144, 2), 256, 0, stream>>>(o2, c3w, c3b, o3b);
  fc_mfma<<<dim3(8, 8), 256, 0, stream>>>(o3b, fcw, fcb, xs);
  gemm_k<false><<<dim3(48, 16), 256, 0, stream>>>(xs, wih, bih, gibuf, 512, 1536, 512);
  hipMemsetAsync(flags, 0, 1024 * sizeof(int), stream);
  gru_k<<<GRU_NB, 256, 0, stream>>>(gibuf, states, masks, whh, bhh, outs, hbuf, flags, out + 1536);
  heads_k<<<128, 256, 0, stream>>>(outs, action, aw, ab, cw, cb, out);
}